// Round 2
// baseline (3325.566 us; speedup 1.0000x reference)
//
#include <hip/hip_runtime.h>
#include <hip/hip_bf16.h>

typedef __hip_bfloat16 bf16;
#define PL 65536          // H*W
#define EPS_LN 1e-6f

__device__ __forceinline__ float fast_tanh(float v){
  float e = __expf(2.f*v);
  return 1.f - 2.f/(e+1.f);
}

// ---------- LN (over 64 channels) fused with 64-out 1x1 conv, bf16 out ----------
__global__ __launch_bounds__(256) void ln_conv64(
    const float* __restrict__ x, const float* __restrict__ lnw,
    const float* __restrict__ lnb, const float* __restrict__ w,
    bf16* __restrict__ out) {
  int p = blockIdx.x * 256 + threadIdx.x;      // 0 .. B*PL-1
  int b = p >> 16, pix = p & 65535;
  const float* xb = x + ((size_t)b * 64) * PL + pix;
  float xn[64];
  float mu = 0.f;
  #pragma unroll
  for (int c = 0; c < 64; ++c) { xn[c] = xb[(size_t)c * PL]; mu += xn[c]; }
  mu *= (1.f/64.f);
  float var = 0.f;
  #pragma unroll
  for (int c = 0; c < 64; ++c) { float d = xn[c]-mu; var += d*d; }
  var *= (1.f/64.f);
  float inv = rsqrtf(var + EPS_LN);
  #pragma unroll
  for (int c = 0; c < 64; ++c) xn[c] = (xn[c]-mu)*inv*lnw[c] + lnb[c];
  bf16* ob = out + ((size_t)b * 64) * PL + pix;
  for (int o = 0; o < 64; ++o) {
    const float* wr = w + o*64;
    float a0=0.f,a1=0.f,a2=0.f,a3=0.f;
    #pragma unroll
    for (int c = 0; c < 64; c += 4) {
      a0 += wr[c+0]*xn[c+0]; a1 += wr[c+1]*xn[c+1];
      a2 += wr[c+2]*xn[c+2]; a3 += wr[c+3]*xn[c+3];
    }
    ob[(size_t)o*PL] = __float2bfloat16((a0+a1)+(a2+a3));
  }
}

// ---------- depthwise 3x3, SAME zero pad, 64 planes/batch, bf16 in/out ----------
__global__ __launch_bounds__(256) void dwconv3(
    const bf16* __restrict__ in, const float* __restrict__ w9,
    bf16* __restrict__ out) {
  int plane = blockIdx.y;                       // 0..B*64-1
  int c = plane & 63;
  int p = blockIdx.x * 256 + threadIdx.x;       // 0..PL-1
  int y = p >> 8, x = p & 255;
  const bf16* ip = in + (size_t)plane * PL;
  const float* wk = w9 + c*9;
  float acc = 0.f;
  #pragma unroll
  for (int i = 0; i < 3; ++i) {
    int yy = y + i - 1;
    if (yy < 0 || yy >= 256) continue;
    #pragma unroll
    for (int j = 0; j < 3; ++j) {
      int xx = x + j - 1;
      if (xx < 0 || xx >= 256) continue;
      acc += wk[i*3+j] * __bfloat162float(ip[yy*256 + xx]);
    }
  }
  out[(size_t)plane*PL + p] = __float2bfloat16(acc);
}

// ---------- stage-1 reduction: per (b,h) Gram(8x8) + sumsq(q),sumsq(k) ----------
__global__ __launch_bounds__(256) void attn_reduce1(
    const bf16* __restrict__ q, const bf16* __restrict__ k,
    float* __restrict__ part) {
  int bh = blockIdx.y;                // b*8+h
  int b = bh >> 3, h = bh & 7;
  int s = blockIdx.x;                 // chunk of 1024 pixels
  int t = threadIdx.x;
  const bf16* qb = q + ((size_t)b*64 + h*8) * PL;
  const bf16* kb = k + ((size_t)b*64 + h*8) * PL;
  float acc[80];
  #pragma unroll
  for (int i=0;i<80;++i) acc[i]=0.f;
  for (int r = 0; r < 4; ++r) {
    int p = s*1024 + r*256 + t;
    float qv[8], kv[8];
    #pragma unroll
    for (int c=0;c<8;++c) {
      qv[c]=__bfloat162float(qb[(size_t)c*PL+p]);
      kv[c]=__bfloat162float(kb[(size_t)c*PL+p]);
    }
    #pragma unroll
    for (int c=0;c<8;++c)
      #pragma unroll
      for (int d=0;d<8;++d) acc[c*8+d] += qv[c]*kv[d];
    #pragma unroll
    for (int c=0;c<8;++c) { acc[64+c] += qv[c]*qv[c]; acc[72+c] += kv[c]*kv[c]; }
  }
  __shared__ float lds[4][80];
  int lane = t & 63, wv = t >> 6;
  #pragma unroll
  for (int i=0;i<80;++i) {
    float v = acc[i];
    for (int off=32; off; off>>=1) v += __shfl_down(v, off);
    if (lane==0) lds[wv][i]=v;
  }
  __syncthreads();
  if (t < 80)
    part[((size_t)bh*64 + s)*80 + t] = lds[0][t]+lds[1][t]+lds[2][t]+lds[3][t];
}

__global__ void attn_reduce2(const float* __restrict__ part, float* __restrict__ red) {
  int bh = blockIdx.x; int t = threadIdx.x;
  if (t < 80) {
    float v = 0.f;
    for (int s=0;s<64;++s) v += part[((size_t)bh*64+s)*80+t];
    red[bh*80+t]=v;
  }
}

// ---------- tiny softmax over 8 per (b,h,c) with l2-normalization folded in ----------
__global__ void attn_softmax(const float* __restrict__ red, const float* __restrict__ temp,
                             float* __restrict__ attn) {
  int bh = threadIdx.x;
  if (bh >= 32) return;
  int h = bh & 7;
  const float* r = red + bh*80;
  float nq[8], nk[8];
  for (int c=0;c<8;++c) nq[c] = fmaxf(sqrtf(r[64+c]), 1e-12f);
  for (int d=0;d<8;++d) nk[d] = fmaxf(sqrtf(r[72+d]), 1e-12f);
  float tm = temp[h];
  for (int c=0;c<8;++c) {
    float a[8]; float m=-1e30f;
    for (int d=0;d<8;++d){ a[d] = r[c*8+d]/(nq[c]*nk[d]) * tm; m=fmaxf(m,a[d]); }
    float ss=0.f;
    for (int d=0;d<8;++d){ a[d]=__expf(a[d]-m); ss+=a[d]; }
    float inv=1.f/ss;
    for (int d=0;d<8;++d) attn[bh*64 + c*8 + d] = a[d]*inv;
  }
}

// ---------- PV (8-way plane mix) + w_proj + residual -> xmid (= d_out) ----------
__global__ __launch_bounds__(256) void attn_out_proj(
    const bf16* __restrict__ vd, const float* __restrict__ attnb,
    const float* __restrict__ wproj, const float* __restrict__ x,
    float* __restrict__ xmid) {
  int p = blockIdx.x * 256 + threadIdx.x;
  int b = p >> 16, pix = p & 65535;
  __shared__ float at[512];
  for (int i=threadIdx.x; i<512; i+=256) at[i]=attnb[b*512+i];
  __syncthreads();
  const bf16* vb = vd + ((size_t)b*64)*PL + pix;
  float oa[64];
  #pragma unroll
  for (int h=0;h<8;++h){
    float vv[8];
    #pragma unroll
    for (int d=0;d<8;++d) vv[d]=__bfloat162float(vb[(size_t)(h*8+d)*PL]);
    #pragma unroll
    for (int c=0;c<8;++c){
      float acc=0.f;
      #pragma unroll
      for (int d=0;d<8;++d) acc += at[h*64+c*8+d]*vv[d];
      oa[h*8+c]=acc;
    }
  }
  const float* xb = x + ((size_t)b*64)*PL + pix;
  float* ob = xmid + ((size_t)b*64)*PL + pix;
  for (int o=0;o<64;++o){
    const float* wr = wproj + o*64;
    float a0=0.f,a1=0.f,a2=0.f,a3=0.f;
    #pragma unroll
    for (int c=0;c<64;c+=4){
      a0 += wr[c+0]*oa[c+0]; a1 += wr[c+1]*oa[c+1];
      a2 += wr[c+2]*oa[c+2]; a3 += wr[c+3]*oa[c+3];
    }
    ob[(size_t)o*PL] = xb[(size_t)o*PL] + (a0+a1)+(a2+a3);
  }
}

// ---------- LN + w_in (340 outs), bf16 output ----------
__global__ __launch_bounds__(256) void ln_conv_in(
    const float* __restrict__ x, const float* __restrict__ lnw,
    const float* __restrict__ lnb, const float* __restrict__ w,
    bf16* __restrict__ t) {
  int p = blockIdx.x * 256 + threadIdx.x;
  int b = p >> 16, pix = p & 65535;
  const float* xb = x + ((size_t)b * 64) * PL + pix;
  float xn[64];
  float mu = 0.f;
  #pragma unroll
  for (int c = 0; c < 64; ++c) { xn[c] = xb[(size_t)c * PL]; mu += xn[c]; }
  mu *= (1.f/64.f);
  float var = 0.f;
  #pragma unroll
  for (int c = 0; c < 64; ++c) { float d = xn[c]-mu; var += d*d; }
  var *= (1.f/64.f);
  float inv = rsqrtf(var + EPS_LN);
  #pragma unroll
  for (int c = 0; c < 64; ++c) xn[c] = (xn[c]-mu)*inv*lnw[c] + lnb[c];
  bf16* tb = t + ((size_t)b * 340) * PL + pix;
  for (int o = 0; o < 340; ++o) {
    const float* wr = w + o*64;
    float a0=0.f,a1=0.f,a2=0.f,a3=0.f;
    #pragma unroll
    for (int c = 0; c < 64; c += 4) {
      a0 += wr[c+0]*xn[c+0]; a1 += wr[c+1]*xn[c+1];
      a2 += wr[c+2]*xn[c+2]; a3 += wr[c+3]*xn[c+3];
    }
    tb[(size_t)o*PL] = __float2bfloat16((a0+a1)+(a2+a3));
  }
}

__global__ void transpose_wout(const float* __restrict__ wout, float* __restrict__ wt){
  for (int i = threadIdx.x; i < 64*170; i += 256) {
    int o = i / 170, hc = i % 170;
    wt[hc*64+o] = wout[i];
  }
}

// ---------- fused IEL: gate chain + w_out matvec + residual, in-place on d_out ----------
__global__ __launch_bounds__(256) void iel_fused(
    const bf16* __restrict__ t, const float* __restrict__ wdw,
    const float* __restrict__ wdw1, const float* __restrict__ wdw2,
    const float* __restrict__ wt, float* __restrict__ out) {
  int p = blockIdx.x * 256 + threadIdx.x;   // 0..B*PL-1
  int b = p >> 16, pix = p & 65535;
  int y = pix >> 8, x = pix & 255;
  float acc[64];
  #pragma unroll
  for (int o=0;o<64;++o) acc[o]=0.f;
  const bf16* tb = t + ((size_t)b*340)*PL;
  for (int hc = 0; hc < 170; ++hc) {
    const bf16* t1 = tb + (size_t)hc * PL;
    const bf16* t2 = tb + (size_t)(170 + hc) * PL;
    float w1[5][5], w2[5][5];
    #pragma unroll
    for (int i=0;i<5;++i){
      int yy = y + i - 2;
      #pragma unroll
      for (int j=0;j<5;++j){
        int xx = x + j - 2;
        bool ok = (yy>=0 && yy<256 && xx>=0 && xx<256);
        int idx = yy*256+xx;
        w1[i][j] = ok ? __bfloat162float(t1[idx]) : 0.f;
        w2[i][j] = ok ? __bfloat162float(t2[idx]) : 0.f;
      }
    }
    const float* k0a = wdw  + hc*9;
    const float* k0b = wdw  + (170+hc)*9;
    const float* k1  = wdw1 + hc*9;
    const float* k2  = wdw2 + hc*9;
    float c2a=0.f, c2b=0.f, d1c=0.f, d2c=0.f;
    #pragma unroll
    for (int dy=0;dy<3;++dy){
      int yy = y + dy - 1;
      #pragma unroll
      for (int dx=0;dx<3;++dx){
        int xx = x + dx - 1;
        bool ok = (yy>=0 && yy<256) && (xx>=0 && xx<256);
        float d1=0.f, d2=0.f;
        if (ok) {
          #pragma unroll
          for (int i=0;i<3;++i)
            #pragma unroll
            for (int j=0;j<3;++j){
              d1 += k0a[i*3+j]*w1[dy+i][dx+j];
              d2 += k0b[i*3+j]*w2[dy+i][dx+j];
            }
        }
        c2a += k1[dy*3+dx]*d1;
        c2b += k2[dy*3+dx]*d2;
        if (dy==1 && dx==1){ d1c=d1; d2c=d2; }
      }
    }
    float pv = (fast_tanh(c2a) + d1c) * (fast_tanh(c2b) + d2c);
    const float* wr = wt + hc*64;
    #pragma unroll
    for (int o=0;o<64;++o) acc[o] += wr[o]*pv;
  }
  float* ob = out + ((size_t)b*64)*PL + pix;
  #pragma unroll
  for (int o=0;o<64;++o) ob[(size_t)o*PL] = ob[(size_t)o*PL] + acc[o];
}

extern "C" void kernel_launch(void* const* d_in, const int* in_sizes, int n_in,
                              void* d_out, int out_size, void* d_ws, size_t ws_size,
                              hipStream_t stream) {
  const float* x      = (const float*)d_in[0];
  const float* y      = (const float*)d_in[1];
  const float* lnw    = (const float*)d_in[2];
  const float* lnb    = (const float*)d_in[3];
  const float* temp   = (const float*)d_in[4];
  const float* wq     = (const float*)d_in[5];
  const float* wq_dw  = (const float*)d_in[6];
  const float* wkv    = (const float*)d_in[7];
  const float* wkv_dw = (const float*)d_in[8];
  const float* wproj  = (const float*)d_in[9];
  const float* w_in   = (const float*)d_in[10];
  const float* w_dw   = (const float*)d_in[11];
  const float* w_dw1  = (const float*)d_in[12];
  const float* w_dw2  = (const float*)d_in[13];
  const float* w_out  = (const float*)d_in[14];

  // ---- arena (byte offsets), peak ~178.3 MB ----
  char* base = (char*)d_ws;
  float* wt   = (float*)(base);                       // 43,520 B (padded to 64K)
  bf16*  pre  = (bf16*)(base + 65536);                // 33,554,432 B
  bf16*  qd   = (bf16*)(base + 65536 + 33554432);     // 33,554,432 B
  bf16*  kd   = (bf16*)(base + 65536 + 67108864);     // 33,554,432 B
  bf16*  vd   = (bf16*)(base + 65536 + 100663296);    // 33,554,432 B
  float* part = (float*)(base + 65536 + 134217728);   // 655,360 B
  float* red  = (float*)(base + 65536 + 134873088);   // 10,240 B
  float* attn = (float*)(base + 65536 + 134883328);   // 8,192 B
  // IEL phase reuses everything from offset 65536 (all CAB scratch dead by then):
  bf16*  tbuf = (bf16*)(base + 65536);                // 178,257,920 B
  float* xmid = (float*)d_out;                        // xmid lives in d_out

  // ---- CAB ----
  ln_conv64<<<1024, 256, 0, stream>>>(x, lnw, lnb, wq, pre);
  dwconv3<<<dim3(256,256), 256, 0, stream>>>(pre, wq_dw, qd);
  ln_conv64<<<1024, 256, 0, stream>>>(y, lnw, lnb, wkv, pre);
  dwconv3<<<dim3(256,256), 256, 0, stream>>>(pre, wkv_dw, kd);
  ln_conv64<<<1024, 256, 0, stream>>>(y, lnw, lnb, wkv + 64*64, pre);
  dwconv3<<<dim3(256,256), 256, 0, stream>>>(pre, wkv_dw + 64*9, vd);
  attn_reduce1<<<dim3(64,32), 256, 0, stream>>>(qd, kd, part);
  attn_reduce2<<<32, 128, 0, stream>>>(part, red);
  attn_softmax<<<1, 64, 0, stream>>>(red, temp, attn);
  attn_out_proj<<<1024, 256, 0, stream>>>(vd, attn, wproj, x, xmid);

  // ---- IEL ----
  ln_conv_in<<<1024, 256, 0, stream>>>(xmid, lnw, lnb, w_in, tbuf);
  transpose_wout<<<1, 256, 0, stream>>>(w_out, wt);
  iel_fused<<<1024, 256, 0, stream>>>(tbuf, w_dw, w_dw1, w_dw2, wt, xmid);
}

// Round 3
// 1678.133 us; speedup vs baseline: 1.9817x; 1.9817x over previous
//
#include <hip/hip_runtime.h>
#include <hip/hip_bf16.h>

typedef __hip_bfloat16 bf16;
#define PL 65536          // H*W
#define EPS_LN 1e-6f

__device__ __forceinline__ float fast_tanh(float v){
  float e = __expf(2.f*v);
  return 1.f - 2.f/(e+1.f);
}

// ---------- LN (over 64 channels) fused with 64-out 1x1 conv, bf16 out ----------
__global__ __launch_bounds__(256) void ln_conv64(
    const float* __restrict__ x, const float* __restrict__ lnw,
    const float* __restrict__ lnb, const float* __restrict__ w,
    bf16* __restrict__ out) {
  int p = blockIdx.x * 256 + threadIdx.x;      // 0 .. B*PL-1
  int b = p >> 16, pix = p & 65535;
  const float* xb = x + ((size_t)b * 64) * PL + pix;
  float xn[64];
  float mu = 0.f;
  #pragma unroll
  for (int c = 0; c < 64; ++c) { xn[c] = xb[(size_t)c * PL]; mu += xn[c]; }
  mu *= (1.f/64.f);
  float var = 0.f;
  #pragma unroll
  for (int c = 0; c < 64; ++c) { float d = xn[c]-mu; var += d*d; }
  var *= (1.f/64.f);
  float inv = rsqrtf(var + EPS_LN);
  #pragma unroll
  for (int c = 0; c < 64; ++c) xn[c] = (xn[c]-mu)*inv*lnw[c] + lnb[c];
  bf16* ob = out + ((size_t)b * 64) * PL + pix;
  for (int o = 0; o < 64; ++o) {
    const float* wr = w + o*64;
    float a0=0.f,a1=0.f,a2=0.f,a3=0.f;
    #pragma unroll
    for (int c = 0; c < 64; c += 4) {
      a0 += wr[c+0]*xn[c+0]; a1 += wr[c+1]*xn[c+1];
      a2 += wr[c+2]*xn[c+2]; a3 += wr[c+3]*xn[c+3];
    }
    ob[(size_t)o*PL] = __float2bfloat16((a0+a1)+(a2+a3));
  }
}

// ---------- depthwise 3x3, SAME zero pad, 64 planes/batch, bf16 in/out ----------
__global__ __launch_bounds__(256) void dwconv3(
    const bf16* __restrict__ in, const float* __restrict__ w9,
    bf16* __restrict__ out) {
  int plane = blockIdx.y;                       // 0..B*64-1
  int c = plane & 63;
  int p = blockIdx.x * 256 + threadIdx.x;       // 0..PL-1
  int y = p >> 8, x = p & 255;
  const bf16* ip = in + (size_t)plane * PL;
  const float* wk = w9 + c*9;
  float acc = 0.f;
  #pragma unroll
  for (int i = 0; i < 3; ++i) {
    int yy = y + i - 1;
    if (yy < 0 || yy >= 256) continue;
    #pragma unroll
    for (int j = 0; j < 3; ++j) {
      int xx = x + j - 1;
      if (xx < 0 || xx >= 256) continue;
      acc += wk[i*3+j] * __bfloat162float(ip[yy*256 + xx]);
    }
  }
  out[(size_t)plane*PL + p] = __float2bfloat16(acc);
}

// ---------- stage-1 reduction: per (b,h) Gram(8x8) + sumsq(q),sumsq(k) ----------
__global__ __launch_bounds__(256) void attn_reduce1(
    const bf16* __restrict__ q, const bf16* __restrict__ k,
    float* __restrict__ part) {
  int bh = blockIdx.y;                // b*8+h
  int b = bh >> 3, h = bh & 7;
  int s = blockIdx.x;                 // chunk of 1024 pixels
  int t = threadIdx.x;
  const bf16* qb = q + ((size_t)b*64 + h*8) * PL;
  const bf16* kb = k + ((size_t)b*64 + h*8) * PL;
  float acc[80];
  #pragma unroll
  for (int i=0;i<80;++i) acc[i]=0.f;
  for (int r = 0; r < 4; ++r) {
    int p = s*1024 + r*256 + t;
    float qv[8], kv[8];
    #pragma unroll
    for (int c=0;c<8;++c) {
      qv[c]=__bfloat162float(qb[(size_t)c*PL+p]);
      kv[c]=__bfloat162float(kb[(size_t)c*PL+p]);
    }
    #pragma unroll
    for (int c=0;c<8;++c)
      #pragma unroll
      for (int d=0;d<8;++d) acc[c*8+d] += qv[c]*kv[d];
    #pragma unroll
    for (int c=0;c<8;++c) { acc[64+c] += qv[c]*qv[c]; acc[72+c] += kv[c]*kv[c]; }
  }
  __shared__ float lds[4][80];
  int lane = t & 63, wv = t >> 6;
  #pragma unroll
  for (int i=0;i<80;++i) {
    float v = acc[i];
    for (int off=32; off; off>>=1) v += __shfl_down(v, off);
    if (lane==0) lds[wv][i]=v;
  }
  __syncthreads();
  if (t < 80)
    part[((size_t)bh*64 + s)*80 + t] = lds[0][t]+lds[1][t]+lds[2][t]+lds[3][t];
}

__global__ void attn_reduce2(const float* __restrict__ part, float* __restrict__ red) {
  int bh = blockIdx.x; int t = threadIdx.x;
  if (t < 80) {
    float v = 0.f;
    for (int s=0;s<64;++s) v += part[((size_t)bh*64+s)*80+t];
    red[bh*80+t]=v;
  }
}

// ---------- tiny softmax over 8 per (b,h,c) with l2-normalization folded in ----------
__global__ void attn_softmax(const float* __restrict__ red, const float* __restrict__ temp,
                             float* __restrict__ attn) {
  int bh = threadIdx.x;
  if (bh >= 32) return;
  int h = bh & 7;
  const float* r = red + bh*80;
  float nq[8], nk[8];
  for (int c=0;c<8;++c) nq[c] = fmaxf(sqrtf(r[64+c]), 1e-12f);
  for (int d=0;d<8;++d) nk[d] = fmaxf(sqrtf(r[72+d]), 1e-12f);
  float tm = temp[h];
  for (int c=0;c<8;++c) {
    float a[8]; float m=-1e30f;
    for (int d=0;d<8;++d){ a[d] = r[c*8+d]/(nq[c]*nk[d]) * tm; m=fmaxf(m,a[d]); }
    float ss=0.f;
    for (int d=0;d<8;++d){ a[d]=__expf(a[d]-m); ss+=a[d]; }
    float inv=1.f/ss;
    for (int d=0;d<8;++d) attn[bh*64 + c*8 + d] = a[d]*inv;
  }
}

// ---------- PV (8-way plane mix) + w_proj + residual -> xmid (= d_out) ----------
__global__ __launch_bounds__(256) void attn_out_proj(
    const bf16* __restrict__ vd, const float* __restrict__ attnb,
    const float* __restrict__ wproj, const float* __restrict__ x,
    float* __restrict__ xmid) {
  int p = blockIdx.x * 256 + threadIdx.x;
  int b = p >> 16, pix = p & 65535;
  __shared__ float at[512];
  for (int i=threadIdx.x; i<512; i+=256) at[i]=attnb[b*512+i];
  __syncthreads();
  const bf16* vb = vd + ((size_t)b*64)*PL + pix;
  float oa[64];
  #pragma unroll
  for (int h=0;h<8;++h){
    float vv[8];
    #pragma unroll
    for (int d=0;d<8;++d) vv[d]=__bfloat162float(vb[(size_t)(h*8+d)*PL]);
    #pragma unroll
    for (int c=0;c<8;++c){
      float acc=0.f;
      #pragma unroll
      for (int d=0;d<8;++d) acc += at[h*64+c*8+d]*vv[d];
      oa[h*8+c]=acc;
    }
  }
  const float* xb = x + ((size_t)b*64)*PL + pix;
  float* ob = xmid + ((size_t)b*64)*PL + pix;
  for (int o=0;o<64;++o){
    const float* wr = wproj + o*64;
    float a0=0.f,a1=0.f,a2=0.f,a3=0.f;
    #pragma unroll
    for (int c=0;c<64;c+=4){
      a0 += wr[c+0]*oa[c+0]; a1 += wr[c+1]*oa[c+1];
      a2 += wr[c+2]*oa[c+2]; a3 += wr[c+3]*oa[c+3];
    }
    ob[(size_t)o*PL] = xb[(size_t)o*PL] + (a0+a1)+(a2+a3);
  }
}

// ---------- LN + w_in (340 outs), bf16 output ----------
__global__ __launch_bounds__(256) void ln_conv_in(
    const float* __restrict__ x, const float* __restrict__ lnw,
    const float* __restrict__ lnb, const float* __restrict__ w,
    bf16* __restrict__ t) {
  int p = blockIdx.x * 256 + threadIdx.x;
  int b = p >> 16, pix = p & 65535;
  const float* xb = x + ((size_t)b * 64) * PL + pix;
  float xn[64];
  float mu = 0.f;
  #pragma unroll
  for (int c = 0; c < 64; ++c) { xn[c] = xb[(size_t)c * PL]; mu += xn[c]; }
  mu *= (1.f/64.f);
  float var = 0.f;
  #pragma unroll
  for (int c = 0; c < 64; ++c) { float d = xn[c]-mu; var += d*d; }
  var *= (1.f/64.f);
  float inv = rsqrtf(var + EPS_LN);
  #pragma unroll
  for (int c = 0; c < 64; ++c) xn[c] = (xn[c]-mu)*inv*lnw[c] + lnb[c];
  bf16* tb = t + ((size_t)b * 340) * PL + pix;
  for (int o = 0; o < 340; ++o) {
    const float* wr = w + o*64;
    float a0=0.f,a1=0.f,a2=0.f,a3=0.f;
    #pragma unroll
    for (int c = 0; c < 64; c += 4) {
      a0 += wr[c+0]*xn[c+0]; a1 += wr[c+1]*xn[c+1];
      a2 += wr[c+2]*xn[c+2]; a3 += wr[c+3]*xn[c+3];
    }
    tb[(size_t)o*PL] = __float2bfloat16((a0+a1)+(a2+a3));
  }
}

__global__ void transpose_wout(const float* __restrict__ wout, float* __restrict__ wt){
  for (int i = threadIdx.x; i < 64*170; i += 256) {
    int o = i / 170, hc = i % 170;
    wt[hc*64+o] = wout[i];
  }
}

// ---------- fused IEL, LDS-tiled: 16x16 pixel tile per 256-thread block ----------
// per hc: stage 20x20 t1/t2 halo -> LDS, compute d=conv3(t) once into 18x18 LDS,
// then per-pixel second conv + tanh gate + w_out matvec accumulation in regs.
__global__ __launch_bounds__(256) void iel_fused(
    const bf16* __restrict__ t, const float* __restrict__ wdw,
    const float* __restrict__ wdw1, const float* __restrict__ wdw2,
    const float* __restrict__ wt, float* __restrict__ out) {
  int b    = blockIdx.y;
  int tile = blockIdx.x;                 // 0..255 (16x16 grid of 16x16 tiles)
  int ty0  = (tile >> 4) << 4;
  int tx0  = (tile & 15) << 4;
  int tid  = threadIdx.x;
  int lr   = tid >> 4;                   // 0..15 (tile-local row)
  int lc   = tid & 15;                   // 0..15 (tile-local col)

  __shared__ float sh_t1[20][21], sh_t2[20][21];
  __shared__ float sh_d1[18][19], sh_d2[18][19];

  float acc[64];
  #pragma unroll
  for (int o=0;o<64;++o) acc[o]=0.f;

  const bf16* tb = t + ((size_t)b*340)*PL;

  for (int hc = 0; hc < 170; ++hc) {
    const bf16* t1 = tb + (size_t)hc * PL;
    const bf16* t2 = tb + (size_t)(170 + hc) * PL;
    // ---- stage halo (origin ty0-2, tx0-2), zero-pad outside image ----
    #pragma unroll
    for (int idx = tid; idx < 400; idx += 256) {
      int r = idx / 20, c = idx % 20;
      int gy = ty0 + r - 2, gx = tx0 + c - 2;
      bool ok = (gy>=0 && gy<256 && gx>=0 && gx<256);
      int gidx = gy*256+gx;
      sh_t1[r][c] = ok ? __bfloat162float(t1[gidx]) : 0.f;
      sh_t2[r][c] = ok ? __bfloat162float(t2[gidx]) : 0.f;
    }
    __syncthreads();
    // ---- d = conv3(t) over 18x18 (origin ty0-1, tx0-1); 0 outside image ----
    const float* k0a = wdw + hc*9;
    const float* k0b = wdw + (170+hc)*9;
    #pragma unroll
    for (int idx = tid; idx < 324; idx += 256) {
      int r = idx / 18, c = idx % 18;
      int gy = ty0 + r - 1, gx = tx0 + c - 1;
      float d1=0.f, d2=0.f;
      if (gy>=0 && gy<256 && gx>=0 && gx<256) {
        #pragma unroll
        for (int i=0;i<3;++i)
          #pragma unroll
          for (int j=0;j<3;++j) {
            d1 += k0a[i*3+j]*sh_t1[r+i][c+j];
            d2 += k0b[i*3+j]*sh_t2[r+i][c+j];
          }
      }
      sh_d1[r][c]=d1; sh_d2[r][c]=d2;
    }
    __syncthreads();
    // ---- second conv + gate + matvec accumulate ----
    const float* k1 = wdw1 + hc*9;
    const float* k2 = wdw2 + hc*9;
    float c2a=0.f, c2b=0.f;
    #pragma unroll
    for (int i=0;i<3;++i)
      #pragma unroll
      for (int j=0;j<3;++j) {
        c2a += k1[i*3+j]*sh_d1[lr+i][lc+j];
        c2b += k2[i*3+j]*sh_d2[lr+i][lc+j];
      }
    float d1c = sh_d1[lr+1][lc+1], d2c = sh_d2[lr+1][lc+1];
    float pv = (fast_tanh(c2a) + d1c) * (fast_tanh(c2b) + d2c);
    const float* wr = wt + hc*64;
    #pragma unroll
    for (int o=0;o<64;++o) acc[o] += wr[o]*pv;
    // no barrier needed here: next halo-load only conflicts with this hc's
    // d-compute (guarded by syncB); next d-compute is behind next syncA.
  }
  int pix = (ty0 + lr)*256 + (tx0 + lc);
  float* ob = out + ((size_t)b*64)*PL + pix;
  #pragma unroll
  for (int o=0;o<64;++o) ob[(size_t)o*PL] = ob[(size_t)o*PL] + acc[o];
}

extern "C" void kernel_launch(void* const* d_in, const int* in_sizes, int n_in,
                              void* d_out, int out_size, void* d_ws, size_t ws_size,
                              hipStream_t stream) {
  const float* x      = (const float*)d_in[0];
  const float* y      = (const float*)d_in[1];
  const float* lnw    = (const float*)d_in[2];
  const float* lnb    = (const float*)d_in[3];
  const float* temp   = (const float*)d_in[4];
  const float* wq     = (const float*)d_in[5];
  const float* wq_dw  = (const float*)d_in[6];
  const float* wkv    = (const float*)d_in[7];
  const float* wkv_dw = (const float*)d_in[8];
  const float* wproj  = (const float*)d_in[9];
  const float* w_in   = (const float*)d_in[10];
  const float* w_dw   = (const float*)d_in[11];
  const float* w_dw1  = (const float*)d_in[12];
  const float* w_dw2  = (const float*)d_in[13];
  const float* w_out  = (const float*)d_in[14];

  // ---- arena (byte offsets), peak ~178.3 MB ----
  char* base = (char*)d_ws;
  float* wt   = (float*)(base);                       // 43,520 B (padded to 64K)
  bf16*  pre  = (bf16*)(base + 65536);                // 33,554,432 B
  bf16*  qd   = (bf16*)(base + 65536 + 33554432);     // 33,554,432 B
  bf16*  kd   = (bf16*)(base + 65536 + 67108864);     // 33,554,432 B
  bf16*  vd   = (bf16*)(base + 65536 + 100663296);    // 33,554,432 B
  float* part = (float*)(base + 65536 + 134217728);   // 655,360 B
  float* red  = (float*)(base + 65536 + 134873088);   // 10,240 B
  float* attn = (float*)(base + 65536 + 134883328);   // 8,192 B
  // IEL phase reuses everything from offset 65536 (all CAB scratch dead by then):
  bf16*  tbuf = (bf16*)(base + 65536);                // 178,257,920 B
  float* xmid = (float*)d_out;                        // xmid lives in d_out

  // ---- CAB ----
  ln_conv64<<<1024, 256, 0, stream>>>(x, lnw, lnb, wq, pre);
  dwconv3<<<dim3(256,256), 256, 0, stream>>>(pre, wq_dw, qd);
  ln_conv64<<<1024, 256, 0, stream>>>(y, lnw, lnb, wkv, pre);
  dwconv3<<<dim3(256,256), 256, 0, stream>>>(pre, wkv_dw, kd);
  ln_conv64<<<1024, 256, 0, stream>>>(y, lnw, lnb, wkv + 64*64, pre);
  dwconv3<<<dim3(256,256), 256, 0, stream>>>(pre, wkv_dw + 64*9, vd);
  attn_reduce1<<<dim3(64,32), 256, 0, stream>>>(qd, kd, part);
  attn_reduce2<<<32, 128, 0, stream>>>(part, red);
  attn_softmax<<<1, 64, 0, stream>>>(red, temp, attn);
  attn_out_proj<<<1024, 256, 0, stream>>>(vd, attn, wproj, x, xmid);

  // ---- IEL ----
  ln_conv_in<<<1024, 256, 0, stream>>>(xmid, lnw, lnb, w_in, tbuf);
  transpose_wout<<<1, 256, 0, stream>>>(w_out, wt);
  iel_fused<<<dim3(256,4), 256, 0, stream>>>(tbuf, w_dw, w_dw1, w_dw2, wt, xmid);
}

// Round 4
// 1203.604 us; speedup vs baseline: 2.7630x; 1.3943x over previous
//
#include <hip/hip_runtime.h>
#include <hip/hip_bf16.h>

typedef __hip_bfloat16 bf16;
typedef unsigned short u16;
typedef __attribute__((ext_vector_type(8))) unsigned short ushort8;
typedef __attribute__((ext_vector_type(8))) short bf16x8;
typedef __attribute__((ext_vector_type(4))) float f32x4;

#define PL 65536          // H*W
#define EPS_LN 1e-6f

__device__ __forceinline__ float fast_tanh(float v){
  float e = __expf(2.f*v);
  return 1.f - 2.f/(e+1.f);
}
__device__ __forceinline__ u16 f2bf(float f){
  bf16 h = __float2bfloat16(f);
  return __builtin_bit_cast(u16, h);
}

// ---------- pack weights to bf16 (and transpose w_out) ----------
__global__ void convert_w(const float* __restrict__ wq, const float* __restrict__ wkv,
                          const float* __restrict__ win, const float* __restrict__ wout,
                          u16* __restrict__ Wq, u16* __restrict__ Wkv,
                          u16* __restrict__ Wp0, u16* __restrict__ Wp1,
                          float* __restrict__ wt){
  int stride = gridDim.x * 256;
  int gid = blockIdx.x * 256 + threadIdx.x;
  for (int i = gid; i < 64*64;  i += stride) Wq[i]  = f2bf(wq[i]);
  for (int i = gid; i < 128*64; i += stride) Wkv[i] = f2bf(wkv[i]);
  for (int i = gid; i < 176*64; i += stride) {
    int r = i >> 6, c = i & 63;
    // pass0: rows 0..84 -> win[r], 85..169 -> win[85+r] (=170+(r-85)), else 0
    Wp0[i] = (r < 85) ? f2bf(win[r*64+c]) : ((r < 170) ? f2bf(win[(85+r)*64+c]) : 0);
    // pass1: rows 0..84 -> win[85+r], 85..169 -> win[170+r] (=255+(r-85)), else 0
    Wp1[i] = (r < 85) ? f2bf(win[(85+r)*64+c]) : ((r < 170) ? f2bf(win[(170+r)*64+c]) : 0);
  }
  for (int i = gid; i < 64*170; i += stride) {
    int o = i / 170, hc = i % 170;
    wt[hc*64+o] = wout[i];
  }
}

// ---------- LN over 64 channels -> pixel-major bf16 [b][PL][64] ----------
__global__ __launch_bounds__(256) void ln_xnorm(
    const float* __restrict__ x, const float* __restrict__ lnw,
    const float* __restrict__ lnb, u16* __restrict__ out) {
  int p = blockIdx.x * 256 + threadIdx.x;      // 0 .. B*PL-1
  int b = p >> 16, pix = p & 65535;
  const float* xb = x + ((size_t)b * 64) * PL + pix;
  float xn[64];
  float mu = 0.f;
  #pragma unroll
  for (int c = 0; c < 64; ++c) { xn[c] = xb[(size_t)c * PL]; mu += xn[c]; }
  mu *= (1.f/64.f);
  float var = 0.f;
  #pragma unroll
  for (int c = 0; c < 64; ++c) { float d = xn[c]-mu; var += d*d; }
  var *= (1.f/64.f);
  float inv = rsqrtf(var + EPS_LN);
  u16* ob = out + ((size_t)b * PL + pix) * 64;
  #pragma unroll
  for (int c8 = 0; c8 < 64; c8 += 8) {
    ushort8 pk;
    #pragma unroll
    for (int j = 0; j < 8; ++j)
      pk[j] = f2bf((xn[c8+j]-mu)*inv*lnw[c8+j] + lnb[c8+j]);
    *reinterpret_cast<ushort8*>(ob + c8) = pk;
  }
}

// ---------- MFMA GEMM: out[b][m][p] = sum_k Wb[m][k] * xn[b][p][k] ----------
// Wb: [MTILES*16][64] bf16 row-major; xn: [b][PL][64] bf16; out: [b][Mvalid][PL] bf16
__global__ __launch_bounds__(256) void gemm64(
    const u16* __restrict__ Wb, const u16* __restrict__ xn,
    u16* __restrict__ out, int MTILES, int Mvalid) {
  int b  = blockIdx.y;
  int p0 = blockIdx.x * 128;
  int tid = threadIdx.x;
  int wv = tid >> 6, lane = tid & 63;
  __shared__ u16 shW[176*72];
  __shared__ u16 shX[128*72];
  const u16* xb = xn + ((size_t)b * PL + p0) * 64;
  for (int idx = tid; idx < 1024; idx += 256) {           // 128 rows x 8 chunks
    int px = idx >> 3, c8 = (idx & 7) << 3;
    *reinterpret_cast<ushort8*>(&shX[px*72 + c8]) =
        *reinterpret_cast<const ushort8*>(xb + px*64 + c8);
  }
  int rows = MTILES << 4;
  for (int idx = tid; idx < rows*8; idx += 256) {
    int r = idx >> 3, c8 = (idx & 7) << 3;
    *reinterpret_cast<ushort8*>(&shW[r*72 + c8]) =
        *reinterpret_cast<const ushort8*>(Wb + r*64 + c8);
  }
  __syncthreads();
  int col = lane & 15, kg = lane >> 4;
  int n0 = wv * 32;
  bf16x8 b00 = *reinterpret_cast<const bf16x8*>(&shX[(n0 + col)*72      + kg*8]);
  bf16x8 b01 = *reinterpret_cast<const bf16x8*>(&shX[(n0 + col)*72 + 32 + kg*8]);
  bf16x8 b10 = *reinterpret_cast<const bf16x8*>(&shX[(n0+16+col)*72      + kg*8]);
  bf16x8 b11 = *reinterpret_cast<const bf16x8*>(&shX[(n0+16+col)*72 + 32 + kg*8]);
  for (int mt = 0; mt < MTILES; ++mt) {
    bf16x8 a0 = *reinterpret_cast<const bf16x8*>(&shW[(mt*16+col)*72      + kg*8]);
    bf16x8 a1 = *reinterpret_cast<const bf16x8*>(&shW[(mt*16+col)*72 + 32 + kg*8]);
    f32x4 acc0 = {0.f,0.f,0.f,0.f}, acc1 = {0.f,0.f,0.f,0.f};
    acc0 = __builtin_amdgcn_mfma_f32_16x16x32_bf16(a0, b00, acc0, 0,0,0);
    acc0 = __builtin_amdgcn_mfma_f32_16x16x32_bf16(a1, b01, acc0, 0,0,0);
    acc1 = __builtin_amdgcn_mfma_f32_16x16x32_bf16(a0, b10, acc1, 0,0,0);
    acc1 = __builtin_amdgcn_mfma_f32_16x16x32_bf16(a1, b11, acc1, 0,0,0);
    int mrow = mt*16 + kg*4;
    #pragma unroll
    for (int r = 0; r < 4; ++r) {
      int ch = mrow + r;
      if (ch < Mvalid) {
        size_t o = ((size_t)b*Mvalid + ch)*PL + p0;
        out[o + n0 + col]      = f2bf(acc0[r]);
        out[o + n0 + 16 + col] = f2bf(acc1[r]);
      }
    }
  }
}

// ---------- depthwise 3x3, SAME zero pad, bf16 in/out ----------
__global__ __launch_bounds__(256) void dwconv3(
    const bf16* __restrict__ in, const float* __restrict__ w9,
    bf16* __restrict__ out, int C) {
  int plane = blockIdx.y;                       // 0..B*C-1
  int c = plane % C;
  int p = blockIdx.x * 256 + threadIdx.x;       // 0..PL-1
  int y = p >> 8, x = p & 255;
  const bf16* ip = in + (size_t)plane * PL;
  const float* wk = w9 + c*9;
  float acc = 0.f;
  #pragma unroll
  for (int i = 0; i < 3; ++i) {
    int yy = y + i - 1;
    if (yy < 0 || yy >= 256) continue;
    #pragma unroll
    for (int j = 0; j < 3; ++j) {
      int xx = x + j - 1;
      if (xx < 0 || xx >= 256) continue;
      acc += wk[i*3+j] * __bfloat162float(ip[yy*256 + xx]);
    }
  }
  out[(size_t)plane*PL + p] = __float2bfloat16(acc);
}

// ---------- stage-1 reduction: per (b,h) Gram(8x8) + sumsq(q),sumsq(k) ----------
// q: [b][64][PL], kv: [b][128][PL] (k = planes 0..63)
__global__ __launch_bounds__(256) void attn_reduce1(
    const bf16* __restrict__ q, const bf16* __restrict__ kv,
    float* __restrict__ part) {
  int bh = blockIdx.y;                // b*8+h
  int b = bh >> 3, h = bh & 7;
  int s = blockIdx.x;                 // chunk of 1024 pixels
  int t = threadIdx.x;
  const bf16* qb = q  + ((size_t)b*64  + h*8) * PL;
  const bf16* kb = kv + ((size_t)b*128 + h*8) * PL;
  float acc[80];
  #pragma unroll
  for (int i=0;i<80;++i) acc[i]=0.f;
  for (int r = 0; r < 4; ++r) {
    int p = s*1024 + r*256 + t;
    float qv[8], kvv[8];
    #pragma unroll
    for (int c=0;c<8;++c) {
      qv[c]=__bfloat162float(qb[(size_t)c*PL+p]);
      kvv[c]=__bfloat162float(kb[(size_t)c*PL+p]);
    }
    #pragma unroll
    for (int c=0;c<8;++c)
      #pragma unroll
      for (int d=0;d<8;++d) acc[c*8+d] += qv[c]*kvv[d];
    #pragma unroll
    for (int c=0;c<8;++c) { acc[64+c] += qv[c]*qv[c]; acc[72+c] += kvv[c]*kvv[c]; }
  }
  __shared__ float lds[4][80];
  int lane = t & 63, wv = t >> 6;
  #pragma unroll
  for (int i=0;i<80;++i) {
    float v = acc[i];
    for (int off=32; off; off>>=1) v += __shfl_down(v, off);
    if (lane==0) lds[wv][i]=v;
  }
  __syncthreads();
  if (t < 80)
    part[((size_t)bh*64 + s)*80 + t] = lds[0][t]+lds[1][t]+lds[2][t]+lds[3][t];
}

__global__ void attn_reduce2(const float* __restrict__ part, float* __restrict__ red) {
  int bh = blockIdx.x; int t = threadIdx.x;
  if (t < 80) {
    float v = 0.f;
    for (int s=0;s<64;++s) v += part[((size_t)bh*64+s)*80+t];
    red[bh*80+t]=v;
  }
}

__global__ void attn_softmax(const float* __restrict__ red, const float* __restrict__ temp,
                             float* __restrict__ attn) {
  int bh = threadIdx.x;
  if (bh >= 32) return;
  int h = bh & 7;
  const float* r = red + bh*80;
  float nq[8], nk[8];
  for (int c=0;c<8;++c) nq[c] = fmaxf(sqrtf(r[64+c]), 1e-12f);
  for (int d=0;d<8;++d) nk[d] = fmaxf(sqrtf(r[72+d]), 1e-12f);
  float tm = temp[h];
  for (int c=0;c<8;++c) {
    float a[8]; float m=-1e30f;
    for (int d=0;d<8;++d){ a[d] = r[c*8+d]/(nq[c]*nk[d]) * tm; m=fmaxf(m,a[d]); }
    float ss=0.f;
    for (int d=0;d<8;++d){ a[d]=__expf(a[d]-m); ss+=a[d]; }
    float inv=1.f/ss;
    for (int d=0;d<8;++d) attn[bh*64 + c*8 + d] = a[d]*inv;
  }
}

// ---------- PV + w_proj + residual -> xmid (= d_out); v = kv planes 64..127 ----------
__global__ __launch_bounds__(256) void attn_out_proj(
    const bf16* __restrict__ kv, const float* __restrict__ attnb,
    const float* __restrict__ wproj, const float* __restrict__ x,
    float* __restrict__ xmid) {
  int p = blockIdx.x * 256 + threadIdx.x;
  int b = p >> 16, pix = p & 65535;
  __shared__ float at[512];
  for (int i=threadIdx.x; i<512; i+=256) at[i]=attnb[b*512+i];
  __syncthreads();
  const bf16* vb = kv + ((size_t)b*128 + 64)*PL + pix;
  float oa[64];
  #pragma unroll
  for (int h=0;h<8;++h){
    float vv[8];
    #pragma unroll
    for (int d=0;d<8;++d) vv[d]=__bfloat162float(vb[(size_t)(h*8+d)*PL]);
    #pragma unroll
    for (int c=0;c<8;++c){
      float acc=0.f;
      #pragma unroll
      for (int d=0;d<8;++d) acc += at[h*64+c*8+d]*vv[d];
      oa[h*8+c]=acc;
    }
  }
  const float* xb = x + ((size_t)b*64)*PL + pix;
  float* ob = xmid + ((size_t)b*64)*PL + pix;
  for (int o=0;o<64;++o){
    const float* wr = wproj + o*64;
    float a0=0.f,a1=0.f,a2=0.f,a3=0.f;
    #pragma unroll
    for (int c=0;c<64;c+=4){
      a0 += wr[c+0]*oa[c+0]; a1 += wr[c+1]*oa[c+1];
      a2 += wr[c+2]*oa[c+2]; a3 += wr[c+3]*oa[c+3];
    }
    ob[(size_t)o*PL] = xb[(size_t)o*PL] + (a0+a1)+(a2+a3);
  }
}

// ---------- fused IEL partial pass (85 channels), LDS-tiled, accumulates into out ----------
// t layout: [b][170][PL]; plane j = t1(hc=hcbase+j), plane 85+j = t2(hc=hcbase+j)
__global__ __launch_bounds__(256) void iel_partial(
    const bf16* __restrict__ t, const float* __restrict__ wdw,
    const float* __restrict__ wdw1, const float* __restrict__ wdw2,
    const float* __restrict__ wt, float* __restrict__ out, int hcbase) {
  int b    = blockIdx.y;
  int tile = blockIdx.x;                 // 0..255
  int ty0  = (tile >> 4) << 4;
  int tx0  = (tile & 15) << 4;
  int tid  = threadIdx.x;
  int lr   = tid >> 4;
  int lc   = tid & 15;

  __shared__ float sh_t1[20][21], sh_t2[20][21];
  __shared__ float sh_d1[18][19], sh_d2[18][19];

  float acc[64];
  #pragma unroll
  for (int o=0;o<64;++o) acc[o]=0.f;

  const bf16* tb = t + ((size_t)b*170)*PL;

  for (int j = 0; j < 85; ++j) {
    int hc = hcbase + j;
    const bf16* t1 = tb + (size_t)j * PL;
    const bf16* t2 = tb + (size_t)(85 + j) * PL;
    #pragma unroll
    for (int idx = tid; idx < 400; idx += 256) {
      int r = idx / 20, c = idx % 20;
      int gy = ty0 + r - 2, gx = tx0 + c - 2;
      bool ok = (gy>=0 && gy<256 && gx>=0 && gx<256);
      int gidx = gy*256+gx;
      sh_t1[r][c] = ok ? __bfloat162float(t1[gidx]) : 0.f;
      sh_t2[r][c] = ok ? __bfloat162float(t2[gidx]) : 0.f;
    }
    __syncthreads();
    const float* k0a = wdw + hc*9;
    const float* k0b = wdw + (170+hc)*9;
    #pragma unroll
    for (int idx = tid; idx < 324; idx += 256) {
      int r = idx / 18, c = idx % 18;
      int gy = ty0 + r - 1, gx = tx0 + c - 1;
      float d1=0.f, d2=0.f;
      if (gy>=0 && gy<256 && gx>=0 && gx<256) {
        #pragma unroll
        for (int i=0;i<3;++i)
          #pragma unroll
          for (int jj=0;jj<3;++jj) {
            d1 += k0a[i*3+jj]*sh_t1[r+i][c+jj];
            d2 += k0b[i*3+jj]*sh_t2[r+i][c+jj];
          }
      }
      sh_d1[r][c]=d1; sh_d2[r][c]=d2;
    }
    __syncthreads();
    const float* k1 = wdw1 + hc*9;
    const float* k2 = wdw2 + hc*9;
    float c2a=0.f, c2b=0.f;
    #pragma unroll
    for (int i=0;i<3;++i)
      #pragma unroll
      for (int jj=0;jj<3;++jj) {
        c2a += k1[i*3+jj]*sh_d1[lr+i][lc+jj];
        c2b += k2[i*3+jj]*sh_d2[lr+i][lc+jj];
      }
    float d1c = sh_d1[lr+1][lc+1], d2c = sh_d2[lr+1][lc+1];
    float pv = (fast_tanh(c2a) + d1c) * (fast_tanh(c2b) + d2c);
    const float* wr = wt + hc*64;
    #pragma unroll
    for (int o=0;o<64;++o) acc[o] += wr[o]*pv;
  }
  int pix = (ty0 + lr)*256 + (tx0 + lc);
  float* ob = out + ((size_t)b*64)*PL + pix;
  #pragma unroll
  for (int o=0;o<64;++o) ob[(size_t)o*PL] = ob[(size_t)o*PL] + acc[o];
}

extern "C" void kernel_launch(void* const* d_in, const int* in_sizes, int n_in,
                              void* d_out, int out_size, void* d_ws, size_t ws_size,
                              hipStream_t stream) {
  const float* x      = (const float*)d_in[0];
  const float* y      = (const float*)d_in[1];
  const float* lnw    = (const float*)d_in[2];
  const float* lnb    = (const float*)d_in[3];
  const float* temp   = (const float*)d_in[4];
  const float* wq     = (const float*)d_in[5];
  const float* wq_dw  = (const float*)d_in[6];
  const float* wkv    = (const float*)d_in[7];
  const float* wkv_dw = (const float*)d_in[8];
  const float* wproj  = (const float*)d_in[9];
  const float* w_in   = (const float*)d_in[10];
  const float* w_dw   = (const float*)d_in[11];
  const float* w_dw1  = (const float*)d_in[12];
  const float* w_dw2  = (const float*)d_in[13];
  const float* w_out  = (const float*)d_in[14];

  // ---- arena: 256KB weight head + 3 data regions (A 32MB, B 64MB, C 64MB) = 160.3MB ----
  char* base = (char*)d_ws;
  u16*   Wq_b  = (u16*)(base + 0);          //  8,192 B
  u16*   Wkv_b = (u16*)(base + 8192);       // 16,384 B
  u16*   Wp0   = (u16*)(base + 24576);      // 22,528 B
  u16*   Wp1   = (u16*)(base + 47104);      // 22,528 B
  float* wt    = (float*)(base + 69632);    // 43,520 B  (ends 113,152)
  char* dataA = base + 262144;              // 33,554,432 B
  char* dataB = base + 262144 + 33554432;   // 67,108,864 B
  char* dataC = base + 262144 + 100663296;  // 67,108,864 B (ends 167,772,160+256K)

  // region A: xny -> xnx -> qd -> xnm
  u16*  xnA   = (u16*)dataA;
  bf16* qd    = (bf16*)dataA;
  // region B: kvpre -> qpre -> attn smalls ; later tbuf (spans B+C)
  u16*  kvpre = (u16*)dataB;
  bf16* kvpreb= (bf16*)dataB;
  u16*  qpre  = (u16*)dataB;
  bf16* qpreb = (bf16*)dataB;
  float* part = (float*)dataB;
  float* red  = (float*)(dataB + 1048576);
  float* attnb= (float*)(dataB + 2097152);
  u16*  tbuf  = (u16*)dataB;                // 89,128,960 B, spans into C
  bf16* tbufb = (bf16*)dataB;
  // region C: kvd
  bf16* kvd   = (bf16*)dataC;
  u16*  kvdu  = (u16*)dataC;
  float* xmid = (float*)d_out;

  convert_w<<<64, 256, 0, stream>>>(wq, wkv, w_in, w_out, Wq_b, Wkv_b, Wp0, Wp1, wt);

  // ---- CAB: kv path then q path ----
  ln_xnorm<<<1024, 256, 0, stream>>>(y, lnw, lnb, xnA);
  gemm64<<<dim3(512,4), 256, 0, stream>>>(Wkv_b, xnA, kvpre, 8, 128);
  dwconv3<<<dim3(256,512), 256, 0, stream>>>(kvpreb, wkv_dw, kvd, 128);
  ln_xnorm<<<1024, 256, 0, stream>>>(x, lnw, lnb, xnA);
  gemm64<<<dim3(512,4), 256, 0, stream>>>(Wq_b, xnA, qpre, 4, 64);
  dwconv3<<<dim3(256,256), 256, 0, stream>>>(qpreb, wq_dw, qd, 64);
  attn_reduce1<<<dim3(64,32), 256, 0, stream>>>(qd, kvd, part);
  attn_reduce2<<<32, 128, 0, stream>>>(part, red);
  attn_softmax<<<1, 64, 0, stream>>>(red, temp, attnb);
  attn_out_proj<<<1024, 256, 0, stream>>>(kvd, attnb, wproj, x, xmid);

  // ---- IEL: two half-channel passes ----
  ln_xnorm<<<1024, 256, 0, stream>>>(xmid, lnw, lnb, xnA);
  gemm64<<<dim3(512,4), 256, 0, stream>>>(Wp0, xnA, tbuf, 11, 170);
  iel_partial<<<dim3(256,4), 256, 0, stream>>>(tbufb, w_dw, w_dw1, w_dw2, wt, xmid, 0);
  gemm64<<<dim3(512,4), 256, 0, stream>>>(Wp1, xnA, tbuf, 11, 170);
  iel_partial<<<dim3(256,4), 256, 0, stream>>>(tbufb, w_dw, w_dw1, w_dw2, wt, xmid, 85);
}

// Round 5
// 1047.874 us; speedup vs baseline: 3.1736x; 1.1486x over previous
//
#include <hip/hip_runtime.h>
#include <hip/hip_bf16.h>

typedef __hip_bfloat16 bf16;
typedef unsigned short u16;
typedef __attribute__((ext_vector_type(8))) unsigned short ushort8;
typedef __attribute__((ext_vector_type(8))) short bf16x8;
typedef __attribute__((ext_vector_type(4))) short bf16x4;
typedef __attribute__((ext_vector_type(4))) float f32x4;

#define PL 65536          // H*W
#define EPS_LN 1e-6f

__device__ __forceinline__ float fast_tanh(float v){
  float e = __expf(2.f*v);
  return 1.f - 2.f/(e+1.f);
}
__device__ __forceinline__ u16 f2bf(float f){
  bf16 h = __float2bfloat16(f);
  return __builtin_bit_cast(u16, h);
}
__device__ __forceinline__ float bf2f(u16 v){
  unsigned int u = ((unsigned int)v) << 16;
  return __builtin_bit_cast(float, u);
}

// ---------- pack weights to bf16 with padding ----------
__global__ void convert_w(const float* __restrict__ wq, const float* __restrict__ wkv,
                          const float* __restrict__ win, const float* __restrict__ wout,
                          const float* __restrict__ wproj,
                          u16* __restrict__ Wq, u16* __restrict__ Wkv,
                          u16* __restrict__ Win, u16* __restrict__ Wout_b,
                          u16* __restrict__ Wproj){
  int stride = gridDim.x * 256;
  int gid = blockIdx.x * 256 + threadIdx.x;
  for (int i = gid; i < 64*64;  i += stride) Wq[i]  = f2bf(wq[i]);
  for (int i = gid; i < 128*64; i += stride) Wkv[i] = f2bf(wkv[i]);
  for (int i = gid; i < 352*64; i += stride) {
    int r = i >> 6;
    Win[i] = (r < 340) ? f2bf(win[i]) : 0;
  }
  for (int i = gid; i < 64*192; i += stride) {
    int o = i / 192, c = i % 192;
    Wout_b[i] = (c < 170) ? f2bf(wout[o*170 + c]) : 0;
  }
  for (int i = gid; i < 64*64; i += stride) Wproj[i] = f2bf(wproj[i]);
}

// ---------- fused LN (64ch) + MFMA GEMM: out[b][m][p] = W[m][:] . LN(x)[p][:] ----------
// x: [b][64][PL] f32; W: [MT*16][64] bf16; out: [b][Mvalid][PL] bf16
__global__ __launch_bounds__(256) void ln_gemm(
    const float* __restrict__ x, const float* __restrict__ lnw,
    const float* __restrict__ lnb, const u16* __restrict__ W,
    u16* __restrict__ out, int MT, int Mvalid) {
  int b  = blockIdx.y;
  int p0 = blockIdx.x * 256;
  int tid = threadIdx.x;
  int lane = tid & 63, wv = tid >> 6;
  __shared__ u16 shX[256][72];          // [px][k], 144B row stride (16B aligned)
  {
    const float* xb = x + ((size_t)b * 64) * PL + p0 + tid;
    float xn[64];
    float mu = 0.f;
    #pragma unroll
    for (int c = 0; c < 64; ++c) { xn[c] = xb[(size_t)c * PL]; mu += xn[c]; }
    mu *= (1.f/64.f);
    float var = 0.f;
    #pragma unroll
    for (int c = 0; c < 64; ++c) { float d = xn[c]-mu; var += d*d; }
    var *= (1.f/64.f);
    float inv = rsqrtf(var + EPS_LN);
    #pragma unroll
    for (int c8 = 0; c8 < 8; ++c8) {
      ushort8 pk;
      #pragma unroll
      for (int j = 0; j < 8; ++j)
        pk[j] = f2bf((xn[c8*8+j]-mu)*inv*lnw[c8*8+j] + lnb[c8*8+j]);
      *reinterpret_cast<ushort8*>(&shX[tid][c8*8]) = pk;
    }
  }
  __syncthreads();
  int col = lane & 15, kg = lane >> 4;
  int n0 = wv * 64;
  bf16x8 bfr[4][2];
  #pragma unroll
  for (int nt = 0; nt < 4; ++nt)
    #pragma unroll
    for (int kh = 0; kh < 2; ++kh)
      bfr[nt][kh] = *reinterpret_cast<const bf16x8*>(&shX[n0 + nt*16 + col][kh*32 + kg*8]);
  for (int mt = 0; mt < MT; ++mt) {
    bf16x8 a0 = *reinterpret_cast<const bf16x8*>(&W[(mt*16+col)*64      + kg*8]);
    bf16x8 a1 = *reinterpret_cast<const bf16x8*>(&W[(mt*16+col)*64 + 32 + kg*8]);
    #pragma unroll
    for (int nt = 0; nt < 4; ++nt) {
      f32x4 acc = {0.f,0.f,0.f,0.f};
      acc = __builtin_amdgcn_mfma_f32_16x16x32_bf16(a0, bfr[nt][0], acc, 0,0,0);
      acc = __builtin_amdgcn_mfma_f32_16x16x32_bf16(a1, bfr[nt][1], acc, 0,0,0);
      int mbase = mt*16 + kg*4;
      #pragma unroll
      for (int r = 0; r < 4; ++r) {
        int ch = mbase + r;
        if (ch < Mvalid)
          out[((size_t)b*Mvalid + ch)*PL + p0 + n0 + nt*16 + col] = f2bf(acc[r]);
      }
    }
  }
}

// ---------- depthwise 3x3, SAME zero pad, bf16 in/out ----------
__global__ __launch_bounds__(256) void dwconv3(
    const bf16* __restrict__ in, const float* __restrict__ w9,
    bf16* __restrict__ out, int C) {
  int plane = blockIdx.y;                       // 0..B*C-1
  int c = plane % C;
  int p = blockIdx.x * 256 + threadIdx.x;       // 0..PL-1
  int y = p >> 8, x = p & 255;
  const bf16* ip = in + (size_t)plane * PL;
  const float* wk = w9 + c*9;
  float acc = 0.f;
  #pragma unroll
  for (int i = 0; i < 3; ++i) {
    int yy = y + i - 1;
    if (yy < 0 || yy >= 256) continue;
    #pragma unroll
    for (int j = 0; j < 3; ++j) {
      int xx = x + j - 1;
      if (xx < 0 || xx >= 256) continue;
      acc += wk[i*3+j] * __bfloat162float(ip[yy*256 + xx]);
    }
  }
  out[(size_t)plane*PL + p] = __float2bfloat16(acc);
}

// ---------- stage-1 reduction: per (b,h) Gram(8x8) + sumsq(q),sumsq(k) ----------
__global__ __launch_bounds__(256) void attn_reduce1(
    const bf16* __restrict__ q, const bf16* __restrict__ kv,
    float* __restrict__ part) {
  int bh = blockIdx.y;                // b*8+h
  int b = bh >> 3, h = bh & 7;
  int s = blockIdx.x;                 // chunk of 1024 pixels
  int t = threadIdx.x;
  const bf16* qb = q  + ((size_t)b*64  + h*8) * PL;
  const bf16* kb = kv + ((size_t)b*128 + h*8) * PL;
  float acc[80];
  #pragma unroll
  for (int i=0;i<80;++i) acc[i]=0.f;
  for (int r = 0; r < 4; ++r) {
    int p = s*1024 + r*256 + t;
    float qv[8], kvv[8];
    #pragma unroll
    for (int c=0;c<8;++c) {
      qv[c]=__bfloat162float(qb[(size_t)c*PL+p]);
      kvv[c]=__bfloat162float(kb[(size_t)c*PL+p]);
    }
    #pragma unroll
    for (int c=0;c<8;++c)
      #pragma unroll
      for (int d=0;d<8;++d) acc[c*8+d] += qv[c]*kvv[d];
    #pragma unroll
    for (int c=0;c<8;++c) { acc[64+c] += qv[c]*qv[c]; acc[72+c] += kvv[c]*kvv[c]; }
  }
  __shared__ float lds[4][80];
  int lane = t & 63, wv = t >> 6;
  #pragma unroll
  for (int i=0;i<80;++i) {
    float v = acc[i];
    for (int off=32; off; off>>=1) v += __shfl_down(v, off);
    if (lane==0) lds[wv][i]=v;
  }
  __syncthreads();
  if (t < 80)
    part[((size_t)bh*64 + s)*80 + t] = lds[0][t]+lds[1][t]+lds[2][t]+lds[3][t];
}

__global__ void attn_reduce2(const float* __restrict__ part, float* __restrict__ red) {
  int bh = blockIdx.x; int t = threadIdx.x;
  if (t < 80) {
    float v = 0.f;
    for (int s=0;s<64;++s) v += part[((size_t)bh*64+s)*80+t];
    red[bh*80+t]=v;
  }
}

__global__ void attn_softmax(const float* __restrict__ red, const float* __restrict__ temp,
                             float* __restrict__ attn) {
  int bh = threadIdx.x;
  if (bh >= 32) return;
  int h = bh & 7;
  const float* r = red + bh*80;
  float nq[8], nk[8];
  for (int c=0;c<8;++c) nq[c] = fmaxf(sqrtf(r[64+c]), 1e-12f);
  for (int d=0;d<8;++d) nk[d] = fmaxf(sqrtf(r[72+d]), 1e-12f);
  float tm = temp[h];
  for (int c=0;c<8;++c) {
    float a[8]; float m=-1e30f;
    for (int d=0;d<8;++d){ a[d] = r[c*8+d]/(nq[c]*nk[d]) * tm; m=fmaxf(m,a[d]); }
    float ss=0.f;
    for (int d=0;d<8;++d){ a[d]=__expf(a[d]-m); ss+=a[d]; }
    float inv=1.f/ss;
    for (int d=0;d<8;++d) attn[bh*64 + c*8 + d] = a[d]*inv;
  }
}

// ---------- PV only -> o pixel-major bf16 [b][PL][64] ----------
__global__ __launch_bounds__(256) void attn_pv(
    const bf16* __restrict__ kv, const float* __restrict__ attnb,
    u16* __restrict__ o_pm) {
  int p = blockIdx.x * 256 + threadIdx.x;
  int b = p >> 16, pix = p & 65535;
  __shared__ float at[512];
  for (int i=threadIdx.x; i<512; i+=256) at[i]=attnb[b*512+i];
  __syncthreads();
  const bf16* vb = kv + ((size_t)b*128 + 64)*PL + pix;
  u16* ob = o_pm + ((size_t)b*PL + pix)*64;
  #pragma unroll
  for (int h=0;h<8;++h){
    float vv[8];
    #pragma unroll
    for (int d=0;d<8;++d) vv[d]=__bfloat162float(vb[(size_t)(h*8+d)*PL]);
    ushort8 pk;
    #pragma unroll
    for (int c=0;c<8;++c){
      float acc=0.f;
      #pragma unroll
      for (int d=0;d<8;++d) acc += at[h*64+c*8+d]*vv[d];
      pk[c] = f2bf(acc);
    }
    *reinterpret_cast<ushort8*>(ob + h*8) = pk;
  }
}

// ---------- MFMA proj: out[b][o][p] = x[b][o][p] + Wp[o][:] . o_pm[p][:] ----------
__global__ __launch_bounds__(256) void gemm_proj(
    const u16* __restrict__ Wp, const u16* __restrict__ o_pm,
    const float* __restrict__ x, float* __restrict__ out) {
  int b  = blockIdx.y;
  int p0 = blockIdx.x * 256;
  int tid = threadIdx.x;
  int lane = tid & 63, wv = tid >> 6;
  __shared__ u16 shX[256][72];
  const u16* src = o_pm + ((size_t)b * PL + p0) * 64;
  #pragma unroll
  for (int c8 = 0; c8 < 8; ++c8)
    *reinterpret_cast<ushort8*>(&shX[tid][c8*8]) =
        *reinterpret_cast<const ushort8*>(src + (size_t)tid*64 + c8*8);
  __syncthreads();
  int col = lane & 15, kg = lane >> 4;
  int n0 = wv * 64;
  bf16x8 bfr[4][2];
  #pragma unroll
  for (int nt = 0; nt < 4; ++nt)
    #pragma unroll
    for (int kh = 0; kh < 2; ++kh)
      bfr[nt][kh] = *reinterpret_cast<const bf16x8*>(&shX[n0 + nt*16 + col][kh*32 + kg*8]);
  #pragma unroll
  for (int mt = 0; mt < 4; ++mt) {
    bf16x8 a0 = *reinterpret_cast<const bf16x8*>(&Wp[(mt*16+col)*64      + kg*8]);
    bf16x8 a1 = *reinterpret_cast<const bf16x8*>(&Wp[(mt*16+col)*64 + 32 + kg*8]);
    #pragma unroll
    for (int nt = 0; nt < 4; ++nt) {
      f32x4 acc = {0.f,0.f,0.f,0.f};
      acc = __builtin_amdgcn_mfma_f32_16x16x32_bf16(a0, bfr[nt][0], acc, 0,0,0);
      acc = __builtin_amdgcn_mfma_f32_16x16x32_bf16(a1, bfr[nt][1], acc, 0,0,0);
      #pragma unroll
      for (int r = 0; r < 4; ++r) {
        int o = mt*16 + kg*4 + r;
        size_t idx = ((size_t)(b*64 + o))*PL + p0 + n0 + nt*16 + col;
        out[idx] = x[idx] + acc[r];
      }
    }
  }
}

// ---------- fused IEL single pass: 4x64 tile, d in LDS, gate -> P panel, MFMA w_out ----------
__global__ __launch_bounds__(256) void iel_v2(
    const u16* __restrict__ t, const float* __restrict__ wdw,
    const float* __restrict__ wdw1, const float* __restrict__ wdw2,
    const u16* __restrict__ Wout, float* __restrict__ out) {
  int b    = blockIdx.y;
  int tile = blockIdx.x;            // 0..255: 64 y-tiles x 4 x-tiles
  int y0 = (tile >> 2) * 4;
  int x0 = (tile & 3) * 64;
  int tid = threadIdx.x;
  int lane = tid & 63, wv = tid >> 6;
  int ly = tid >> 6, lx = tid & 63;
  int col = lane & 15, kg = lane >> 4;

  __shared__ float sh_t1[8][72], sh_t2[8][72];   // halo: rows y0-2..y0+5, cols x0-2..x0+65
  __shared__ float sh_d1[6][69], sh_d2[6][69];   // d: rows y0-1..y0+4, cols x0-1..x0+64
  __shared__ u16  shP[256][36];                  // [px][kk] bf16 panel (K-chunk 32)

  f32x4 acc[4][4];
  #pragma unroll
  for (int mt=0;mt<4;++mt)
    #pragma unroll
    for (int nt=0;nt<4;++nt) acc[mt][nt] = (f32x4){0.f,0.f,0.f,0.f};

  const u16* tb1 = t + (size_t)b*340*PL;
  const u16* tb2 = tb1 + (size_t)170*PL;

  // precompute halo positions (loop-invariant)
  int hr[3], hcol[3], hg[3];        // hg = global offset or -1
  #pragma unroll
  for (int i=0;i<3;++i){
    int idx = tid + i*256;
    hr[i] = idx/68; hcol[i] = idx%68;
    int gy = y0 + hr[i] - 2, gx = x0 + hcol[i] - 2;
    hg[i] = (idx < 544 && gy>=0 && gy<256 && gx>=0 && gx<256) ? (gy*256+gx) : -1;
  }
  u16 h1[3], h2[3];
  #pragma unroll
  for (int i=0;i<3;++i){
    h1[i] = (hg[i] >= 0) ? tb1[hg[i]] : (u16)0;
    h2[i] = (hg[i] >= 0) ? tb2[hg[i]] : (u16)0;
  }

  for (int chunk = 0; chunk < 6; ++chunk) {
    for (int kk = 0; kk < 32; ++kk) {
      int hc = chunk*32 + kk;
      if (hc < 170) {
        // write staged halo regs to LDS
        #pragma unroll
        for (int i=0;i<3;++i){
          int idx = tid + i*256;
          if (idx < 544){
            sh_t1[hr[i]][hcol[i]] = bf2f(h1[i]);
            sh_t2[hr[i]][hcol[i]] = bf2f(h2[i]);
          }
        }
        __syncthreads();
        // prefetch next hc's halo
        if (hc + 1 < 170) {
          const u16* p1 = tb1 + (size_t)(hc+1)*PL;
          const u16* p2 = tb2 + (size_t)(hc+1)*PL;
          #pragma unroll
          for (int i=0;i<3;++i){
            h1[i] = (hg[i] >= 0) ? p1[hg[i]] : (u16)0;
            h2[i] = (hg[i] >= 0) ? p2[hg[i]] : (u16)0;
          }
        }
        // d = conv3(t), zero outside image
        const float* k0a = wdw + hc*9;
        const float* k0b = wdw + (170+hc)*9;
        #pragma unroll
        for (int it=0; it<2; ++it){
          int idx = tid + it*256;
          if (idx < 396){
            int r = idx/66, c = idx%66;
            int gy = y0 + r - 1, gx = x0 + c - 1;
            float d1=0.f, d2=0.f;
            if (gy>=0 && gy<256 && gx>=0 && gx<256){
              #pragma unroll
              for (int i=0;i<3;++i)
                #pragma unroll
                for (int j=0;j<3;++j){
                  d1 += k0a[i*3+j]*sh_t1[r+i][c+j];
                  d2 += k0b[i*3+j]*sh_t2[r+i][c+j];
                }
            }
            sh_d1[r][c]=d1; sh_d2[r][c]=d2;
          }
        }
        __syncthreads();
        // gate
        const float* k1 = wdw1 + hc*9;
        const float* k2 = wdw2 + hc*9;
        float c2a=0.f, c2b=0.f;
        #pragma unroll
        for (int i=0;i<3;++i)
          #pragma unroll
          for (int j=0;j<3;++j){
            c2a += k1[i*3+j]*sh_d1[ly+i][lx+j];
            c2b += k2[i*3+j]*sh_d2[ly+i][lx+j];
          }
        float d1c = sh_d1[ly+1][lx+1], d2c = sh_d2[ly+1][lx+1];
        float pv = (fast_tanh(c2a) + d1c) * (fast_tanh(c2b) + d2c);
        shP[tid][kk] = f2bf(pv);
      } else {
        shP[tid][kk] = 0;           // zero-pad K (uniform branch, no barriers)
      }
    }
    __syncthreads();                // P panel complete
    // MFMA: acc[mt][nt] += Wout[:, chunk] . P
    #pragma unroll
    for (int nt = 0; nt < 4; ++nt) {
      int px = wv*64 + nt*16 + col;
      const bf16x4* pp = reinterpret_cast<const bf16x4*>(&shP[px][kg*8]);
      bf16x4 plo = pp[0], phi = pp[1];
      bf16x8 bfrag;
      #pragma unroll
      for (int j=0;j<4;++j){ bfrag[j]=plo[j]; bfrag[4+j]=phi[j]; }
      #pragma unroll
      for (int mt = 0; mt < 4; ++mt) {
        bf16x8 a = *reinterpret_cast<const bf16x8*>(&Wout[(mt*16+col)*192 + chunk*32 + kg*8]);
        acc[mt][nt] = __builtin_amdgcn_mfma_f32_16x16x32_bf16(a, bfrag, acc[mt][nt], 0,0,0);
      }
    }
    // no barrier needed: next shP writes are >=2 barriers away (and rows are thread-private)
  }
  // epilogue: residual RMW on out (each (o,pix) touched by exactly one lane)
  int prow = y0 + wv;
  #pragma unroll
  for (int mt=0; mt<4; ++mt)
    #pragma unroll
    for (int nt=0; nt<4; ++nt)
      #pragma unroll
      for (int r=0; r<4; ++r){
        int o = mt*16 + kg*4 + r;
        size_t idx = ((size_t)(b*64 + o))*PL + prow*256 + x0 + nt*16 + col;
        out[idx] += acc[mt][nt][r];
      }
}

extern "C" void kernel_launch(void* const* d_in, const int* in_sizes, int n_in,
                              void* d_out, int out_size, void* d_ws, size_t ws_size,
                              hipStream_t stream) {
  const float* x      = (const float*)d_in[0];
  const float* y      = (const float*)d_in[1];
  const float* lnw    = (const float*)d_in[2];
  const float* lnb    = (const float*)d_in[3];
  const float* temp   = (const float*)d_in[4];
  const float* wq     = (const float*)d_in[5];
  const float* wq_dw  = (const float*)d_in[6];
  const float* wkv    = (const float*)d_in[7];
  const float* wkv_dw = (const float*)d_in[8];
  const float* wproj  = (const float*)d_in[9];
  const float* w_in   = (const float*)d_in[10];
  const float* w_dw   = (const float*)d_in[11];
  const float* w_dw1  = (const float*)d_in[12];
  const float* w_dw2  = (const float*)d_in[13];
  const float* w_out  = (const float*)d_in[14];

  // ---- arena: 128KB weight head + data (peak ~178.4 MB) ----
  char* base = (char*)d_ws;
  u16* Wq_b    = (u16*)(base + 0);        //  8,192 B
  u16* Wkv_b   = (u16*)(base + 8192);     // 16,384 B
  u16* Win_b   = (u16*)(base + 24576);    // 45,056 B
  u16* Wout_b  = (u16*)(base + 69632);    // 24,576 B
  u16* Wproj_b = (u16*)(base + 94208);    //  8,192 B (head ends 102,400)
  char* A  = base + 131072;               // 67,108,864 B region
  char* Br = A + 67108864;                // 67,108,864 B region
  u16*  kvpre = (u16*)A;                  // 67 MB   [b][128][PL]
  u16*  qpre  = (u16*)A;                  // 33.5 MB [b][64][PL] (kvpre dead)
  u16*  qd    = (u16*)(A + 33554432);     // 33.5 MB
  float* part = (float*)A;                // 655 KB (qpre dead)
  float* red  = (float*)(A + 1048576);    // 10 KB
  float* attnb= (float*)(A + 1572864);    //  2 KB
  u16*  o_pm  = (u16*)(A + 2097152);      // 33.5 MB (qd dead)
  u16*  kvd   = (u16*)Br;                 // 67 MB
  u16*  tbuf  = (u16*)A;                  // 178,257,920 B [b][340][PL] (all CAB dead)
  float* xmid = (float*)d_out;

  convert_w<<<64, 256, 0, stream>>>(wq, wkv, w_in, w_out, wproj,
                                    Wq_b, Wkv_b, Win_b, Wout_b, Wproj_b);

  // ---- CAB ----
  ln_gemm<<<dim3(256,4), 256, 0, stream>>>(y, lnw, lnb, Wkv_b, kvpre, 8, 128);
  dwconv3<<<dim3(256,512), 256, 0, stream>>>((const bf16*)kvpre, wkv_dw, (bf16*)kvd, 128);
  ln_gemm<<<dim3(256,4), 256, 0, stream>>>(x, lnw, lnb, Wq_b, qpre, 4, 64);
  dwconv3<<<dim3(256,256), 256, 0, stream>>>((const bf16*)qpre, wq_dw, (bf16*)qd, 64);
  attn_reduce1<<<dim3(64,32), 256, 0, stream>>>((const bf16*)qd, (const bf16*)kvd, part);
  attn_reduce2<<<32, 128, 0, stream>>>(part, red);
  attn_softmax<<<1, 64, 0, stream>>>(red, temp, attnb);
  attn_pv<<<1024, 256, 0, stream>>>((const bf16*)kvd, attnb, o_pm);
  gemm_proj<<<dim3(256,4), 256, 0, stream>>>(Wproj_b, o_pm, x, xmid);

  // ---- IEL ----
  ln_gemm<<<dim3(256,4), 256, 0, stream>>>(xmid, lnw, lnb, Win_b, tbuf, 22, 340);
  iel_v2<<<dim3(256,4), 256, 0, stream>>>(tbuf, w_dw, w_dw1, w_dw2, Wout_b, xmid);
}

// Round 6
// 869.251 us; speedup vs baseline: 3.8258x; 1.2055x over previous
//
#include <hip/hip_runtime.h>
#include <hip/hip_bf16.h>

typedef __hip_bfloat16 bf16;
typedef unsigned short u16;
typedef __attribute__((ext_vector_type(8))) unsigned short ushort8;
typedef __attribute__((ext_vector_type(8))) short bf16x8;
typedef __attribute__((ext_vector_type(4))) short bf16x4;
typedef __attribute__((ext_vector_type(4))) float f32x4;

#define PL 65536          // H*W
#define EPS_LN 1e-6f

__device__ __forceinline__ float fast_tanh(float v){
  float e = __expf(2.f*v);
  return 1.f - 2.f/(e+1.f);
}
__device__ __forceinline__ u16 f2bf(float f){
  bf16 h = __float2bfloat16(f);
  return __builtin_bit_cast(u16, h);
}
__device__ __forceinline__ float bf2f(u16 v){
  unsigned int u = ((unsigned int)v) << 16;
  return __builtin_bit_cast(float, u);
}

// ---------- pack weights to bf16 with padding / reorder ----------
__global__ void convert_w(const float* __restrict__ wq, const float* __restrict__ wkv,
                          const float* __restrict__ win, const float* __restrict__ wout,
                          const float* __restrict__ wproj,
                          u16* __restrict__ Wq, u16* __restrict__ Wkv,
                          u16* __restrict__ Wp0, u16* __restrict__ Wp1,
                          u16* __restrict__ Wproj,
                          u16* __restrict__ Wh0, u16* __restrict__ Wh1){
  int stride = gridDim.x * 256;
  int gid = blockIdx.x * 256 + threadIdx.x;
  for (int i = gid; i < 64*64;  i += stride) Wq[i]  = f2bf(wq[i]);
  for (int i = gid; i < 128*64; i += stride) Wkv[i] = f2bf(wkv[i]);
  for (int i = gid; i < 176*64; i += stride) {
    int r = i >> 6, c = i & 63;
    // half0 channels: rows 0..84 -> win[r] (t1_j), rows 85..169 -> win[170+(r-85)] (t2_j)
    Wp0[i] = (r < 85) ? f2bf(win[r*64+c]) : ((r < 170) ? f2bf(win[(85+r)*64+c]) : 0);
    // half1 channels: rows 0..84 -> win[85+r], rows 85..169 -> win[255+(r-85)]
    Wp1[i] = (r < 85) ? f2bf(win[(85+r)*64+c]) : ((r < 170) ? f2bf(win[(170+r)*64+c]) : 0);
  }
  for (int i = gid; i < 64*64; i += stride) Wproj[i] = f2bf(wproj[i]);
  for (int i = gid; i < 64*96; i += stride) {
    int o = i / 96, c = i % 96;
    Wh0[i] = (c < 85) ? f2bf(wout[o*170 + c]) : 0;
    Wh1[i] = (c < 85) ? f2bf(wout[o*170 + 85 + c]) : 0;
  }
}

// ---------- fused LN (64ch) + MFMA GEMM: out[b][m][p] = W[m][:] . LN(x)[p][:] ----------
__global__ __launch_bounds__(256) void ln_gemm(
    const float* __restrict__ x, const float* __restrict__ lnw,
    const float* __restrict__ lnb, const u16* __restrict__ W,
    u16* __restrict__ out, int MT, int Mvalid) {
  int b  = blockIdx.y;
  int p0 = blockIdx.x * 256;
  int tid = threadIdx.x;
  int lane = tid & 63, wv = tid >> 6;
  __shared__ u16 shX[256][72];
  {
    const float* xb = x + ((size_t)b * 64) * PL + p0 + tid;
    float xn[64];
    float mu = 0.f;
    #pragma unroll
    for (int c = 0; c < 64; ++c) { xn[c] = xb[(size_t)c * PL]; mu += xn[c]; }
    mu *= (1.f/64.f);
    float var = 0.f;
    #pragma unroll
    for (int c = 0; c < 64; ++c) { float d = xn[c]-mu; var += d*d; }
    var *= (1.f/64.f);
    float inv = rsqrtf(var + EPS_LN);
    #pragma unroll
    for (int c8 = 0; c8 < 8; ++c8) {
      ushort8 pk;
      #pragma unroll
      for (int j = 0; j < 8; ++j)
        pk[j] = f2bf((xn[c8*8+j]-mu)*inv*lnw[c8*8+j] + lnb[c8*8+j]);
      *reinterpret_cast<ushort8*>(&shX[tid][c8*8]) = pk;
    }
  }
  __syncthreads();
  int col = lane & 15, kg = lane >> 4;
  int n0 = wv * 64;
  bf16x8 bfr[4][2];
  #pragma unroll
  for (int nt = 0; nt < 4; ++nt)
    #pragma unroll
    for (int kh = 0; kh < 2; ++kh)
      bfr[nt][kh] = *reinterpret_cast<const bf16x8*>(&shX[n0 + nt*16 + col][kh*32 + kg*8]);
  for (int mt = 0; mt < MT; ++mt) {
    bf16x8 a0 = *reinterpret_cast<const bf16x8*>(&W[(mt*16+col)*64      + kg*8]);
    bf16x8 a1 = *reinterpret_cast<const bf16x8*>(&W[(mt*16+col)*64 + 32 + kg*8]);
    #pragma unroll
    for (int nt = 0; nt < 4; ++nt) {
      f32x4 acc = {0.f,0.f,0.f,0.f};
      acc = __builtin_amdgcn_mfma_f32_16x16x32_bf16(a0, bfr[nt][0], acc, 0,0,0);
      acc = __builtin_amdgcn_mfma_f32_16x16x32_bf16(a1, bfr[nt][1], acc, 0,0,0);
      int mbase = mt*16 + kg*4;
      #pragma unroll
      for (int r = 0; r < 4; ++r) {
        int ch = mbase + r;
        if (ch < Mvalid)
          out[((size_t)b*Mvalid + ch)*PL + p0 + n0 + nt*16 + col] = f2bf(acc[r]);
      }
    }
  }
}

// ---------- LN over 64 channels -> pixel-major bf16 [b][PL][64] ----------
__global__ __launch_bounds__(256) void ln_xnorm(
    const float* __restrict__ x, const float* __restrict__ lnw,
    const float* __restrict__ lnb, u16* __restrict__ out) {
  int p = blockIdx.x * 256 + threadIdx.x;
  int b = p >> 16, pix = p & 65535;
  const float* xb = x + ((size_t)b * 64) * PL + pix;
  float xn[64];
  float mu = 0.f;
  #pragma unroll
  for (int c = 0; c < 64; ++c) { xn[c] = xb[(size_t)c * PL]; mu += xn[c]; }
  mu *= (1.f/64.f);
  float var = 0.f;
  #pragma unroll
  for (int c = 0; c < 64; ++c) { float d = xn[c]-mu; var += d*d; }
  var *= (1.f/64.f);
  float inv = rsqrtf(var + EPS_LN);
  u16* ob = out + ((size_t)b * PL + pix) * 64;
  #pragma unroll
  for (int c8 = 0; c8 < 64; c8 += 8) {
    ushort8 pk;
    #pragma unroll
    for (int j = 0; j < 8; ++j)
      pk[j] = f2bf((xn[c8+j]-mu)*inv*lnw[c8+j] + lnb[c8+j]);
    *reinterpret_cast<ushort8*>(ob + c8) = pk;
  }
}

// ---------- MFMA GEMM from pixel-major xn: out[b][m][p] = W[m][:] . xn[p][:] ----------
__global__ __launch_bounds__(256) void gemm64(
    const u16* __restrict__ Wb, const u16* __restrict__ xn,
    u16* __restrict__ out, int MTILES, int Mvalid) {
  int b  = blockIdx.y;
  int p0 = blockIdx.x * 128;
  int tid = threadIdx.x;
  int wv = tid >> 6, lane = tid & 63;
  __shared__ u16 shW[176*72];
  __shared__ u16 shX[128*72];
  const u16* xb = xn + ((size_t)b * PL + p0) * 64;
  for (int idx = tid; idx < 1024; idx += 256) {
    int px = idx >> 3, c8 = (idx & 7) << 3;
    *reinterpret_cast<ushort8*>(&shX[px*72 + c8]) =
        *reinterpret_cast<const ushort8*>(xb + px*64 + c8);
  }
  int rows = MTILES << 4;
  for (int idx = tid; idx < rows*8; idx += 256) {
    int r = idx >> 3, c8 = (idx & 7) << 3;
    *reinterpret_cast<ushort8*>(&shW[r*72 + c8]) =
        *reinterpret_cast<const ushort8*>(Wb + r*64 + c8);
  }
  __syncthreads();
  int col = lane & 15, kg = lane >> 4;
  int n0 = wv * 32;
  bf16x8 b00 = *reinterpret_cast<const bf16x8*>(&shX[(n0 + col)*72      + kg*8]);
  bf16x8 b01 = *reinterpret_cast<const bf16x8*>(&shX[(n0 + col)*72 + 32 + kg*8]);
  bf16x8 b10 = *reinterpret_cast<const bf16x8*>(&shX[(n0+16+col)*72      + kg*8]);
  bf16x8 b11 = *reinterpret_cast<const bf16x8*>(&shX[(n0+16+col)*72 + 32 + kg*8]);
  for (int mt = 0; mt < MTILES; ++mt) {
    bf16x8 a0 = *reinterpret_cast<const bf16x8*>(&shW[(mt*16+col)*72      + kg*8]);
    bf16x8 a1 = *reinterpret_cast<const bf16x8*>(&shW[(mt*16+col)*72 + 32 + kg*8]);
    f32x4 acc0 = {0.f,0.f,0.f,0.f}, acc1 = {0.f,0.f,0.f,0.f};
    acc0 = __builtin_amdgcn_mfma_f32_16x16x32_bf16(a0, b00, acc0, 0,0,0);
    acc0 = __builtin_amdgcn_mfma_f32_16x16x32_bf16(a1, b01, acc0, 0,0,0);
    acc1 = __builtin_amdgcn_mfma_f32_16x16x32_bf16(a0, b10, acc1, 0,0,0);
    acc1 = __builtin_amdgcn_mfma_f32_16x16x32_bf16(a1, b11, acc1, 0,0,0);
    int mrow = mt*16 + kg*4;
    #pragma unroll
    for (int r = 0; r < 4; ++r) {
      int ch = mrow + r;
      if (ch < Mvalid) {
        size_t o = ((size_t)b*Mvalid + ch)*PL + p0;
        out[o + n0 + col]      = f2bf(acc0[r]);
        out[o + n0 + 16 + col] = f2bf(acc1[r]);
      }
    }
  }
}

// ---------- depthwise 3x3, SAME zero pad, bf16 in/out ----------
__global__ __launch_bounds__(256) void dwconv3(
    const bf16* __restrict__ in, const float* __restrict__ w9,
    bf16* __restrict__ out, int C) {
  int plane = blockIdx.y;
  int c = plane % C;
  int p = blockIdx.x * 256 + threadIdx.x;
  int y = p >> 8, x = p & 255;
  const bf16* ip = in + (size_t)plane * PL;
  const float* wk = w9 + c*9;
  float acc = 0.f;
  #pragma unroll
  for (int i = 0; i < 3; ++i) {
    int yy = y + i - 1;
    if (yy < 0 || yy >= 256) continue;
    #pragma unroll
    for (int j = 0; j < 3; ++j) {
      int xx = x + j - 1;
      if (xx < 0 || xx >= 256) continue;
      acc += wk[i*3+j] * __bfloat162float(ip[yy*256 + xx]);
    }
  }
  out[(size_t)plane*PL + p] = __float2bfloat16(acc);
}

// ---------- stage-1 reduction: per (b,h) Gram(8x8) + sumsq(q),sumsq(k) ----------
__global__ __launch_bounds__(256) void attn_reduce1(
    const bf16* __restrict__ q, const bf16* __restrict__ kv,
    float* __restrict__ part) {
  int bh = blockIdx.y;
  int b = bh >> 3, h = bh & 7;
  int s = blockIdx.x;
  int t = threadIdx.x;
  const bf16* qb = q  + ((size_t)b*64  + h*8) * PL;
  const bf16* kb = kv + ((size_t)b*128 + h*8) * PL;
  float acc[80];
  #pragma unroll
  for (int i=0;i<80;++i) acc[i]=0.f;
  for (int r = 0; r < 4; ++r) {
    int p = s*1024 + r*256 + t;
    float qv[8], kvv[8];
    #pragma unroll
    for (int c=0;c<8;++c) {
      qv[c]=__bfloat162float(qb[(size_t)c*PL+p]);
      kvv[c]=__bfloat162float(kb[(size_t)c*PL+p]);
    }
    #pragma unroll
    for (int c=0;c<8;++c)
      #pragma unroll
      for (int d=0;d<8;++d) acc[c*8+d] += qv[c]*kvv[d];
    #pragma unroll
    for (int c=0;c<8;++c) { acc[64+c] += qv[c]*qv[c]; acc[72+c] += kvv[c]*kvv[c]; }
  }
  __shared__ float lds[4][80];
  int lane = t & 63, wv = t >> 6;
  #pragma unroll
  for (int i=0;i<80;++i) {
    float v = acc[i];
    for (int off=32; off; off>>=1) v += __shfl_down(v, off);
    if (lane==0) lds[wv][i]=v;
  }
  __syncthreads();
  if (t < 80)
    part[((size_t)bh*64 + s)*80 + t] = lds[0][t]+lds[1][t]+lds[2][t]+lds[3][t];
}

__global__ void attn_reduce2(const float* __restrict__ part, float* __restrict__ red) {
  int bh = blockIdx.x; int t = threadIdx.x;
  if (t < 80) {
    float v = 0.f;
    for (int s=0;s<64;++s) v += part[((size_t)bh*64+s)*80+t];
    red[bh*80+t]=v;
  }
}

__global__ void attn_softmax(const float* __restrict__ red, const float* __restrict__ temp,
                             float* __restrict__ attn) {
  int bh = threadIdx.x;
  if (bh >= 32) return;
  int h = bh & 7;
  const float* r = red + bh*80;
  float nq[8], nk[8];
  for (int c=0;c<8;++c) nq[c] = fmaxf(sqrtf(r[64+c]), 1e-12f);
  for (int d=0;d<8;++d) nk[d] = fmaxf(sqrtf(r[72+d]), 1e-12f);
  float tm = temp[h];
  for (int c=0;c<8;++c) {
    float a[8]; float m=-1e30f;
    for (int d=0;d<8;++d){ a[d] = r[c*8+d]/(nq[c]*nk[d]) * tm; m=fmaxf(m,a[d]); }
    float ss=0.f;
    for (int d=0;d<8;++d){ a[d]=__expf(a[d]-m); ss+=a[d]; }
    float inv=1.f/ss;
    for (int d=0;d<8;++d) attn[bh*64 + c*8 + d] = a[d]*inv;
  }
}

// ---------- PV only -> o pixel-major bf16 [b][PL][64] ----------
__global__ __launch_bounds__(256) void attn_pv(
    const bf16* __restrict__ kv, const float* __restrict__ attnb,
    u16* __restrict__ o_pm) {
  int p = blockIdx.x * 256 + threadIdx.x;
  int b = p >> 16, pix = p & 65535;
  __shared__ float at[512];
  for (int i=threadIdx.x; i<512; i+=256) at[i]=attnb[b*512+i];
  __syncthreads();
  const bf16* vb = kv + ((size_t)b*128 + 64)*PL + pix;
  u16* ob = o_pm + ((size_t)b*PL + pix)*64;
  #pragma unroll
  for (int h=0;h<8;++h){
    float vv[8];
    #pragma unroll
    for (int d=0;d<8;++d) vv[d]=__bfloat162float(vb[(size_t)(h*8+d)*PL]);
    ushort8 pk;
    #pragma unroll
    for (int c=0;c<8;++c){
      float acc=0.f;
      #pragma unroll
      for (int d=0;d<8;++d) acc += at[h*64+c*8+d]*vv[d];
      pk[c] = f2bf(acc);
    }
    *reinterpret_cast<ushort8*>(ob + h*8) = pk;
  }
}

// ---------- MFMA proj: out[b][o][p] = x[b][o][p] + Wp[o][:] . o_pm[p][:] ----------
__global__ __launch_bounds__(256) void gemm_proj(
    const u16* __restrict__ Wp, const u16* __restrict__ o_pm,
    const float* __restrict__ x, float* __restrict__ out) {
  int b  = blockIdx.y;
  int p0 = blockIdx.x * 256;
  int tid = threadIdx.x;
  int lane = tid & 63, wv = tid >> 6;
  __shared__ u16 shX[256][72];
  const u16* src = o_pm + ((size_t)b * PL + p0) * 64;
  #pragma unroll
  for (int c8 = 0; c8 < 8; ++c8)
    *reinterpret_cast<ushort8*>(&shX[tid][c8*8]) =
        *reinterpret_cast<const ushort8*>(src + (size_t)tid*64 + c8*8);
  __syncthreads();
  int col = lane & 15, kg = lane >> 4;
  int n0 = wv * 64;
  bf16x8 bfr[4][2];
  #pragma unroll
  for (int nt = 0; nt < 4; ++nt)
    #pragma unroll
    for (int kh = 0; kh < 2; ++kh)
      bfr[nt][kh] = *reinterpret_cast<const bf16x8*>(&shX[n0 + nt*16 + col][kh*32 + kg*8]);
  #pragma unroll
  for (int mt = 0; mt < 4; ++mt) {
    bf16x8 a0 = *reinterpret_cast<const bf16x8*>(&Wp[(mt*16+col)*64      + kg*8]);
    bf16x8 a1 = *reinterpret_cast<const bf16x8*>(&Wp[(mt*16+col)*64 + 32 + kg*8]);
    #pragma unroll
    for (int nt = 0; nt < 4; ++nt) {
      f32x4 acc = {0.f,0.f,0.f,0.f};
      acc = __builtin_amdgcn_mfma_f32_16x16x32_bf16(a0, bfr[nt][0], acc, 0,0,0);
      acc = __builtin_amdgcn_mfma_f32_16x16x32_bf16(a1, bfr[nt][1], acc, 0,0,0);
      #pragma unroll
      for (int r = 0; r < 4; ++r) {
        int o = mt*16 + kg*4 + r;
        size_t idx = ((size_t)(b*64 + o))*PL + p0 + n0 + nt*16 + col;
        out[idx] = x[idx] + acc[r];
      }
    }
  }
}

// ---------- IEL gate: one (plane-pair, 8x32 tile) per block -> pv plane-major ----------
// t: [b][170][PL] (planes 0..84 = t1_j, 85..169 = t2_j for this half)
__global__ __launch_bounds__(256) void iel_gate(
    const u16* __restrict__ t, const float* __restrict__ wdw,
    const float* __restrict__ wdw1, const float* __restrict__ wdw2,
    u16* __restrict__ P, int hcbase) {
  int pj = blockIdx.y;                  // 0..B*85-1
  int b = pj / 85, j = pj % 85;
  int hc = hcbase + j;
  int bx = blockIdx.x;                  // 0..255: 32 y-tiles x 8 x-tiles
  int ty = (bx >> 3) * 8, tx = (bx & 7) * 32;
  int tid = threadIdx.x;

  __shared__ float s1[12][37], s2[12][37];     // t halo rows ty-2..ty+9, cols tx-2..tx+33
  __shared__ float d1s[10][35], d2s[10][35];   // d rows ty-1..ty+8, cols tx-1..tx+32

  const u16* t1 = t + (size_t)(b*170 + j) * PL;
  const u16* t2 = t + (size_t)(b*170 + 85 + j) * PL;
  #pragma unroll
  for (int i = 0; i < 2; ++i) {
    int idx = tid + i*256;
    if (idx < 432) {
      int r = idx / 36, c = idx % 36;
      int gy = ty + r - 2, gx = tx + c - 2;
      bool ok = (gy>=0 && gy<256 && gx>=0 && gx<256);
      int g = gy*256 + gx;
      s1[r][c] = ok ? bf2f(t1[g]) : 0.f;
      s2[r][c] = ok ? bf2f(t2[g]) : 0.f;
    }
  }
  __syncthreads();
  const float* k0a = wdw + hc*9;
  const float* k0b = wdw + (170+hc)*9;
  #pragma unroll
  for (int i = 0; i < 2; ++i) {
    int idx = tid + i*256;
    if (idx < 340) {
      int r = idx / 34, c = idx % 34;
      int gy = ty + r - 1, gx = tx + c - 1;
      float a = 0.f, bb = 0.f;
      if (gy>=0 && gy<256 && gx>=0 && gx<256) {
        #pragma unroll
        for (int ii=0;ii<3;++ii)
          #pragma unroll
          for (int jj=0;jj<3;++jj) {
            a  += k0a[ii*3+jj]*s1[r+ii][c+jj];
            bb += k0b[ii*3+jj]*s2[r+ii][c+jj];
          }
      }
      d1s[r][c] = a; d2s[r][c] = bb;
    }
  }
  __syncthreads();
  int ly = tid >> 5, lx = tid & 31;
  const float* k1 = wdw1 + hc*9;
  const float* k2 = wdw2 + hc*9;
  float c2a = 0.f, c2b = 0.f;
  #pragma unroll
  for (int ii=0;ii<3;++ii)
    #pragma unroll
    for (int jj=0;jj<3;++jj) {
      c2a += k1[ii*3+jj]*d1s[ly+ii][lx+jj];
      c2b += k2[ii*3+jj]*d2s[ly+ii][lx+jj];
    }
  float d1c = d1s[ly+1][lx+1], d2c = d2s[ly+1][lx+1];
  float pv = (fast_tanh(c2a) + d1c) * (fast_tanh(c2b) + d2c);
  P[(size_t)pj*PL + (ty+ly)*256 + tx + lx] = f2bf(pv);
}

// ---------- IEL out-GEMM: out[b][o][px] += Wh[o][:] . P[b][:][px], K=85 pad 96 ----------
__global__ __launch_bounds__(256) void iel_gemm(
    const u16* __restrict__ Wh, const u16* __restrict__ P,
    float* __restrict__ out) {
  int b  = blockIdx.y;
  int p0 = blockIdx.x * 256;
  int tid = threadIdx.x;
  int lane = tid & 63, wv = tid >> 6;
  int col = lane & 15, kg = lane >> 4;
  int n0 = wv * 64;
  __shared__ u16 shP[256][36];
  f32x4 acc[4][4];
  #pragma unroll
  for (int mt=0;mt<4;++mt)
    #pragma unroll
    for (int nt=0;nt<4;++nt) acc[mt][nt] = (f32x4){0.f,0.f,0.f,0.f};

  int kk = tid & 31, q = tid >> 5;
  for (int c = 0; c < 3; ++c) {
    int hcl = c*32 + kk;
    ushort8 v[4];
    if (hcl < 85) {
      const u16* src = P + (size_t)(b*85 + hcl)*PL + p0 + q*32;
      #pragma unroll
      for (int jj=0;jj<4;++jj) v[jj] = *reinterpret_cast<const ushort8*>(src + jj*8);
    } else {
      #pragma unroll
      for (int jj=0;jj<4;++jj) v[jj] = (ushort8){0,0,0,0,0,0,0,0};
    }
    __syncthreads();            // previous chunk's MFMA reads complete
    #pragma unroll
    for (int jj=0;jj<4;++jj)
      #pragma unroll
      for (int i=0;i<8;++i) shP[q*32 + jj*8 + i][kk] = v[jj][i];
    __syncthreads();
    #pragma unroll
    for (int nt = 0; nt < 4; ++nt) {
      int px = n0 + nt*16 + col;
      const bf16x4* pp = reinterpret_cast<const bf16x4*>(&shP[px][kg*8]);
      bf16x4 plo = pp[0], phi = pp[1];
      bf16x8 bfrag;
      #pragma unroll
      for (int jj=0;jj<4;++jj){ bfrag[jj]=plo[jj]; bfrag[4+jj]=phi[jj]; }
      #pragma unroll
      for (int mt = 0; mt < 4; ++mt) {
        bf16x8 a = *reinterpret_cast<const bf16x8*>(&Wh[(mt*16+col)*96 + c*32 + kg*8]);
        acc[mt][nt] = __builtin_amdgcn_mfma_f32_16x16x32_bf16(a, bfrag, acc[mt][nt], 0,0,0);
      }
    }
  }
  #pragma unroll
  for (int mt=0; mt<4; ++mt)
    #pragma unroll
    for (int nt=0; nt<4; ++nt)
      #pragma unroll
      for (int r=0; r<4; ++r){
        int o = mt*16 + kg*4 + r;
        size_t idx = ((size_t)(b*64 + o))*PL + p0 + n0 + nt*16 + col;
        out[idx] += acc[mt][nt][r];
      }
}

extern "C" void kernel_launch(void* const* d_in, const int* in_sizes, int n_in,
                              void* d_out, int out_size, void* d_ws, size_t ws_size,
                              hipStream_t stream) {
  const float* x      = (const float*)d_in[0];
  const float* y      = (const float*)d_in[1];
  const float* lnw    = (const float*)d_in[2];
  const float* lnb    = (const float*)d_in[3];
  const float* temp   = (const float*)d_in[4];
  const float* wq     = (const float*)d_in[5];
  const float* wq_dw  = (const float*)d_in[6];
  const float* wkv    = (const float*)d_in[7];
  const float* wkv_dw = (const float*)d_in[8];
  const float* wproj  = (const float*)d_in[9];
  const float* w_in   = (const float*)d_in[10];
  const float* w_dw   = (const float*)d_in[11];
  const float* w_dw1  = (const float*)d_in[12];
  const float* w_dw2  = (const float*)d_in[13];
  const float* w_out  = (const float*)d_in[14];

  // ---- arena: 128KB weight head + R1(67M) + R2(67M) + R3(33.5M) = 160.1 MB peak ----
  char* base = (char*)d_ws;
  u16* Wq_b    = (u16*)(base + 0);        //  8,192 B
  u16* Wkv_b   = (u16*)(base + 8192);     // 16,384 B
  u16* Wp0     = (u16*)(base + 24576);    // 22,528 B
  u16* Wp1     = (u16*)(base + 47104);    // 22,528 B
  u16* Wproj_b = (u16*)(base + 69632);    //  8,192 B
  u16* Wh0     = (u16*)(base + 77824);    // 12,288 B
  u16* Wh1     = (u16*)(base + 90112);    // 12,288 B (head ends 102,400)
  char* R1 = base + 131072;               // 67,108,864 B
  char* R2 = R1 + 67108864;               // 67,108,864 B
  char* R3 = R2 + 67108864;               // 33,554,432 B

  // CAB phase
  u16*  kvpre = (u16*)R1;                 // 67 MB [b][128][PL]
  u16*  qpre  = (u16*)R1;                 // 33.5 MB (kvpre dead)
  u16*  qd    = (u16*)(R1 + 33554432);    // 33.5 MB
  float* part = (float*)R1;               // 655 KB (qpre dead)
  float* red  = (float*)(R1 + 1048576);
  float* attnb= (float*)(R1 + 1572864);
  u16*  o_pm  = (u16*)(R1 + 2097152);     // 33.5 MB (overlaps dead qd tail only after reduce1)
  u16*  kvd   = (u16*)R2;                 // 67 MB
  // IEL phase (all CAB scratch dead)
  u16*  xnm   = (u16*)R3;                 // 33.5 MB pixel-major LN(xmid)
  u16*  tbufH = (u16*)R1;                 // 89,128,960 B [b][170][PL] (spans into R2)
  u16*  Pbuf  = (u16*)(R1 + 89128960);    // 44,564,480 B [b*85][PL] (ends at R1+133.7MB)
  float* xmid = (float*)d_out;

  convert_w<<<64, 256, 0, stream>>>(wq, wkv, w_in, w_out, wproj,
                                    Wq_b, Wkv_b, Wp0, Wp1, Wproj_b, Wh0, Wh1);

  // ---- CAB ----
  ln_gemm<<<dim3(256,4), 256, 0, stream>>>(y, lnw, lnb, Wkv_b, kvpre, 8, 128);
  dwconv3<<<dim3(256,512), 256, 0, stream>>>((const bf16*)kvpre, wkv_dw, (bf16*)kvd, 128);
  ln_gemm<<<dim3(256,4), 256, 0, stream>>>(x, lnw, lnb, Wq_b, qpre, 4, 64);
  dwconv3<<<dim3(256,256), 256, 0, stream>>>((const bf16*)qpre, wq_dw, (bf16*)qd, 64);
  attn_reduce1<<<dim3(64,32), 256, 0, stream>>>((const bf16*)qd, (const bf16*)kvd, part);
  attn_reduce2<<<32, 128, 0, stream>>>(part, red);
  attn_softmax<<<1, 64, 0, stream>>>(red, temp, attnb);
  attn_pv<<<1024, 256, 0, stream>>>((const bf16*)kvd, attnb, o_pm);
  gemm_proj<<<dim3(256,4), 256, 0, stream>>>(Wproj_b, o_pm, x, xmid);

  // ---- IEL: capture LN(xmid), then two 85-channel half passes ----
  ln_xnorm<<<1024, 256, 0, stream>>>(xmid, lnw, lnb, xnm);
  gemm64<<<dim3(512,4), 256, 0, stream>>>(Wp0, xnm, tbufH, 11, 170);
  iel_gate<<<dim3(256,340), 256, 0, stream>>>(tbufH, w_dw, w_dw1, w_dw2, Pbuf, 0);
  iel_gemm<<<dim3(256,4), 256, 0, stream>>>(Wh0, Pbuf, xmid);
  gemm64<<<dim3(512,4), 256, 0, stream>>>(Wp1, xnm, tbufH, 11, 170);
  iel_gate<<<dim3(256,340), 256, 0, stream>>>(tbufH, w_dw, w_dw1, w_dw2, Pbuf, 85);
  iel_gemm<<<dim3(256,4), 256, 0, stream>>>(Wh1, Pbuf, xmid);
}

// Round 7
// 571.242 us; speedup vs baseline: 5.8216x; 1.5217x over previous
//
#include <hip/hip_runtime.h>
#include <hip/hip_bf16.h>

typedef __hip_bfloat16 bf16;
typedef unsigned short u16;
typedef __attribute__((ext_vector_type(8))) unsigned short ushort8;
typedef __attribute__((ext_vector_type(8))) short bf16x8;
typedef __attribute__((ext_vector_type(4))) short bf16x4;
typedef __attribute__((ext_vector_type(4))) float f32x4;

#define PL 65536          // H*W
#define EPS_LN 1e-6f

__device__ __forceinline__ float fast_tanh(float v){
  float e = __expf(2.f*v);
  return 1.f - 2.f/(e+1.f);
}
__device__ __forceinline__ u16 f2bf(float f){
  bf16 h = __float2bfloat16(f);
  return __builtin_bit_cast(u16, h);
}
__device__ __forceinline__ float bf2f(u16 v){
  unsigned int u = ((unsigned int)v) << 16;
  return __builtin_bit_cast(float, u);
}

// ---------- pack weights to bf16 with padding / reorder ----------
__global__ void convert_w(const float* __restrict__ wq, const float* __restrict__ wkv,
                          const float* __restrict__ win, const float* __restrict__ wout,
                          const float* __restrict__ wproj,
                          u16* __restrict__ Wq, u16* __restrict__ Wkv,
                          u16* __restrict__ Wp0, u16* __restrict__ Wp1,
                          u16* __restrict__ Wproj, u16* __restrict__ Wh){
  int stride = gridDim.x * 256;
  int gid = blockIdx.x * 256 + threadIdx.x;
  for (int i = gid; i < 64*64;  i += stride) Wq[i]  = f2bf(wq[i]);
  for (int i = gid; i < 128*64; i += stride) Wkv[i] = f2bf(wkv[i]);
  for (int i = gid; i < 176*64; i += stride) {
    int r = i >> 6, c = i & 63;
    // half0 rows: 0..84 -> win[r] (t1_j), 85..169 -> win[170+(r-85)] (t2_j)
    Wp0[i] = (r < 85) ? f2bf(win[r*64+c]) : ((r < 170) ? f2bf(win[(85+r)*64+c]) : 0);
    // half1 rows: 0..84 -> win[85+r], 85..169 -> win[255+(r-85)]
    Wp1[i] = (r < 85) ? f2bf(win[(85+r)*64+c]) : ((r < 170) ? f2bf(win[(170+r)*64+c]) : 0);
  }
  for (int i = gid; i < 64*64; i += stride) Wproj[i] = f2bf(wproj[i]);
  for (int i = gid; i < 64*192; i += stride) {
    int o = i / 192, c = i % 192;
    Wh[i] = (c < 170) ? f2bf(wout[o*170 + c]) : 0;
  }
}

// ---------- fused LN (64ch) + MFMA GEMM: out[b][m][p] = W[m][:] . LN(x)[p][:] ----------
__global__ __launch_bounds__(256) void ln_gemm(
    const float* __restrict__ x, const float* __restrict__ lnw,
    const float* __restrict__ lnb, const u16* __restrict__ W,
    u16* __restrict__ out, int MT, int Mvalid) {
  int b  = blockIdx.y;
  int p0 = blockIdx.x * 256;
  int tid = threadIdx.x;
  int lane = tid & 63, wv = tid >> 6;
  __shared__ u16 shX[256][72];
  {
    const float* xb = x + ((size_t)b * 64) * PL + p0 + tid;
    float xn[64];
    float mu = 0.f;
    #pragma unroll
    for (int c = 0; c < 64; ++c) { xn[c] = xb[(size_t)c * PL]; mu += xn[c]; }
    mu *= (1.f/64.f);
    float var = 0.f;
    #pragma unroll
    for (int c = 0; c < 64; ++c) { float d = xn[c]-mu; var += d*d; }
    var *= (1.f/64.f);
    float inv = rsqrtf(var + EPS_LN);
    #pragma unroll
    for (int c8 = 0; c8 < 8; ++c8) {
      ushort8 pk;
      #pragma unroll
      for (int j = 0; j < 8; ++j)
        pk[j] = f2bf((xn[c8*8+j]-mu)*inv*lnw[c8*8+j] + lnb[c8*8+j]);
      *reinterpret_cast<ushort8*>(&shX[tid][c8*8]) = pk;
    }
  }
  __syncthreads();
  int col = lane & 15, kg = lane >> 4;
  int n0 = wv * 64;
  bf16x8 bfr[4][2];
  #pragma unroll
  for (int nt = 0; nt < 4; ++nt)
    #pragma unroll
    for (int kh = 0; kh < 2; ++kh)
      bfr[nt][kh] = *reinterpret_cast<const bf16x8*>(&shX[n0 + nt*16 + col][kh*32 + kg*8]);
  for (int mt = 0; mt < MT; ++mt) {
    bf16x8 a0 = *reinterpret_cast<const bf16x8*>(&W[(mt*16+col)*64      + kg*8]);
    bf16x8 a1 = *reinterpret_cast<const bf16x8*>(&W[(mt*16+col)*64 + 32 + kg*8]);
    #pragma unroll
    for (int nt = 0; nt < 4; ++nt) {
      f32x4 acc = {0.f,0.f,0.f,0.f};
      acc = __builtin_amdgcn_mfma_f32_16x16x32_bf16(a0, bfr[nt][0], acc, 0,0,0);
      acc = __builtin_amdgcn_mfma_f32_16x16x32_bf16(a1, bfr[nt][1], acc, 0,0,0);
      int mbase = mt*16 + kg*4;
      #pragma unroll
      for (int r = 0; r < 4; ++r) {
        int ch = mbase + r;
        if (ch < Mvalid)
          out[((size_t)b*Mvalid + ch)*PL + p0 + n0 + nt*16 + col] = f2bf(acc[r]);
      }
    }
  }
}

// ---------- vectorized depthwise 3x3, SAME zero pad: 8-row x 256-col tile ----------
__global__ __launch_bounds__(256) void dwconv3v(
    const u16* __restrict__ in, const float* __restrict__ w9,
    u16* __restrict__ out, int C) {
  int plane = blockIdx.y;               // 0..B*C-1
  int cch = plane % C;
  int y0 = blockIdx.x * 8;              // 32 tiles
  int tid = threadIdx.x;
  const u16* ip = in + (size_t)plane * PL;
  __shared__ u16 sh[10][272];           // rows y0-1..y0+8; image col g at LDS col g+8
  #pragma unroll
  for (int i = 0; i < 2; ++i) {
    int idx = tid + i*256;
    if (idx < 320) {
      int r = idx >> 5, seg = idx & 31;
      int gy = y0 - 1 + r;
      ushort8 v = {0,0,0,0,0,0,0,0};
      if (gy >= 0 && gy < 256)
        v = *reinterpret_cast<const ushort8*>(ip + gy*256 + seg*8);
      *reinterpret_cast<ushort8*>(&sh[r][8 + seg*8]) = v;
    }
  }
  if (tid < 10) { sh[tid][7] = 0; sh[tid][264] = 0; }
  __syncthreads();
  float wk[9];
  #pragma unroll
  for (int i=0;i<9;++i) wk[i] = w9[cch*9+i];
  int lr = tid >> 5, xs = (tid & 31) * 8;
  float row[3][10];
  #pragma unroll
  for (int i = 0; i < 3; ++i) {
    ushort8 m = *reinterpret_cast<const ushort8*>(&sh[lr+i][8+xs]);
    row[i][0] = bf2f(sh[lr+i][7+xs]);
    #pragma unroll
    for (int j=0;j<8;++j) row[i][1+j] = bf2f((u16)m[j]);
    row[i][9] = bf2f(sh[lr+i][16+xs]);
  }
  ushort8 o;
  #pragma unroll
  for (int j = 0; j < 8; ++j) {
    float a = 0.f;
    #pragma unroll
    for (int i=0;i<3;++i)
      #pragma unroll
      for (int k=0;k<3;++k) a += wk[i*3+k]*row[i][j+k];
    o[j] = f2bf(a);
  }
  int gy = y0 + lr;
  *reinterpret_cast<ushort8*>(out + (size_t)plane*PL + gy*256 + xs) = o;
}

// ---------- stage-1 reduction: per (b,h) Gram(8x8) + sumsq(q),sumsq(k) ----------
__global__ __launch_bounds__(256) void attn_reduce1(
    const bf16* __restrict__ q, const bf16* __restrict__ kv,
    float* __restrict__ part) {
  int bh = blockIdx.y;
  int b = bh >> 3, h = bh & 7;
  int s = blockIdx.x;
  int t = threadIdx.x;
  const bf16* qb = q  + ((size_t)b*64  + h*8) * PL;
  const bf16* kb = kv + ((size_t)b*128 + h*8) * PL;
  float acc[80];
  #pragma unroll
  for (int i=0;i<80;++i) acc[i]=0.f;
  for (int r = 0; r < 4; ++r) {
    int p = s*1024 + r*256 + t;
    float qv[8], kvv[8];
    #pragma unroll
    for (int c=0;c<8;++c) {
      qv[c]=__bfloat162float(qb[(size_t)c*PL+p]);
      kvv[c]=__bfloat162float(kb[(size_t)c*PL+p]);
    }
    #pragma unroll
    for (int c=0;c<8;++c)
      #pragma unroll
      for (int d=0;d<8;++d) acc[c*8+d] += qv[c]*kvv[d];
    #pragma unroll
    for (int c=0;c<8;++c) { acc[64+c] += qv[c]*qv[c]; acc[72+c] += kvv[c]*kvv[c]; }
  }
  __shared__ float lds[4][80];
  int lane = t & 63, wv = t >> 6;
  #pragma unroll
  for (int i=0;i<80;++i) {
    float v = acc[i];
    for (int off=32; off; off>>=1) v += __shfl_down(v, off);
    if (lane==0) lds[wv][i]=v;
  }
  __syncthreads();
  if (t < 80)
    part[((size_t)bh*64 + s)*80 + t] = lds[0][t]+lds[1][t]+lds[2][t]+lds[3][t];
}

__global__ void attn_reduce2(const float* __restrict__ part, float* __restrict__ red) {
  int bh = blockIdx.x; int t = threadIdx.x;
  if (t < 80) {
    float v = 0.f;
    for (int s=0;s<64;++s) v += part[((size_t)bh*64+s)*80+t];
    red[bh*80+t]=v;
  }
}

__global__ void attn_softmax(const float* __restrict__ red, const float* __restrict__ temp,
                             float* __restrict__ attn) {
  int bh = threadIdx.x;
  if (bh >= 32) return;
  int h = bh & 7;
  const float* r = red + bh*80;
  float nq[8], nk[8];
  for (int c=0;c<8;++c) nq[c] = fmaxf(sqrtf(r[64+c]), 1e-12f);
  for (int d=0;d<8;++d) nk[d] = fmaxf(sqrtf(r[72+d]), 1e-12f);
  float tm = temp[h];
  for (int c=0;c<8;++c) {
    float a[8]; float m=-1e30f;
    for (int d=0;d<8;++d){ a[d] = r[c*8+d]/(nq[c]*nk[d]) * tm; m=fmaxf(m,a[d]); }
    float ss=0.f;
    for (int d=0;d<8;++d){ a[d]=__expf(a[d]-m); ss+=a[d]; }
    float inv=1.f/ss;
    for (int d=0;d<8;++d) attn[bh*64 + c*8 + d] = a[d]*inv;
  }
}

// ---------- PV only -> o pixel-major bf16 [b][PL][64] ----------
__global__ __launch_bounds__(256) void attn_pv(
    const bf16* __restrict__ kv, const float* __restrict__ attnb,
    u16* __restrict__ o_pm) {
  int p = blockIdx.x * 256 + threadIdx.x;
  int b = p >> 16, pix = p & 65535;
  __shared__ float at[512];
  for (int i=threadIdx.x; i<512; i+=256) at[i]=attnb[b*512+i];
  __syncthreads();
  const bf16* vb = kv + ((size_t)b*128 + 64)*PL + pix;
  u16* ob = o_pm + ((size_t)b*PL + pix)*64;
  #pragma unroll
  for (int h=0;h<8;++h){
    float vv[8];
    #pragma unroll
    for (int d=0;d<8;++d) vv[d]=__bfloat162float(vb[(size_t)(h*8+d)*PL]);
    ushort8 pk;
    #pragma unroll
    for (int c=0;c<8;++c){
      float acc=0.f;
      #pragma unroll
      for (int d=0;d<8;++d) acc += at[h*64+c*8+d]*vv[d];
      pk[c] = f2bf(acc);
    }
    *reinterpret_cast<ushort8*>(ob + h*8) = pk;
  }
}

// ---------- MFMA proj: out[b][o][p] = x[b][o][p] + Wp[o][:] . o_pm[p][:] ----------
__global__ __launch_bounds__(256) void gemm_proj(
    const u16* __restrict__ Wp, const u16* __restrict__ o_pm,
    const float* __restrict__ x, float* __restrict__ out) {
  int b  = blockIdx.y;
  int p0 = blockIdx.x * 256;
  int tid = threadIdx.x;
  int lane = tid & 63, wv = tid >> 6;
  __shared__ u16 shX[256][72];
  const u16* src = o_pm + ((size_t)b * PL + p0) * 64;
  #pragma unroll
  for (int c8 = 0; c8 < 8; ++c8)
    *reinterpret_cast<ushort8*>(&shX[tid][c8*8]) =
        *reinterpret_cast<const ushort8*>(src + (size_t)tid*64 + c8*8);
  __syncthreads();
  int col = lane & 15, kg = lane >> 4;
  int n0 = wv * 64;
  bf16x8 bfr[4][2];
  #pragma unroll
  for (int nt = 0; nt < 4; ++nt)
    #pragma unroll
    for (int kh = 0; kh < 2; ++kh)
      bfr[nt][kh] = *reinterpret_cast<const bf16x8*>(&shX[n0 + nt*16 + col][kh*32 + kg*8]);
  #pragma unroll
  for (int mt = 0; mt < 4; ++mt) {
    bf16x8 a0 = *reinterpret_cast<const bf16x8*>(&Wp[(mt*16+col)*64      + kg*8]);
    bf16x8 a1 = *reinterpret_cast<const bf16x8*>(&Wp[(mt*16+col)*64 + 32 + kg*8]);
    #pragma unroll
    for (int nt = 0; nt < 4; ++nt) {
      f32x4 acc = {0.f,0.f,0.f,0.f};
      acc = __builtin_amdgcn_mfma_f32_16x16x32_bf16(a0, bfr[nt][0], acc, 0,0,0);
      acc = __builtin_amdgcn_mfma_f32_16x16x32_bf16(a1, bfr[nt][1], acc, 0,0,0);
      #pragma unroll
      for (int r = 0; r < 4; ++r) {
        int o = mt*16 + kg*4 + r;
        size_t idx = ((size_t)(b*64 + o))*PL + p0 + n0 + nt*16 + col;
        out[idx] = x[idx] + acc[r];
      }
    }
  }
}

// ---------- IEL gate: one (plane-pair, 8x32 tile) per block -> pv plane-major ----------
// t: [b][170][PL] (planes 0..84 = t1_j, 85..169 = t2_j for this half)
// P: [b][170][PL], this half writes planes hcbase..hcbase+84
__global__ __launch_bounds__(256) void iel_gate(
    const u16* __restrict__ t, const float* __restrict__ wdw,
    const float* __restrict__ wdw1, const float* __restrict__ wdw2,
    u16* __restrict__ P, int hcbase) {
  int pj = blockIdx.y;                  // 0..B*85-1
  int b = pj / 85, j = pj % 85;
  int hc = hcbase + j;
  int bx = blockIdx.x;                  // 0..255: 32 y-tiles x 8 x-tiles
  int ty = (bx >> 3) * 8, tx = (bx & 7) * 32;
  int tid = threadIdx.x;

  __shared__ float s1[12][56], s2[12][56];     // image col g at LDS col g-(tx-8)
  __shared__ float d1s[10][35], d2s[10][35];   // d rows ty-1..ty+8, cols tx-1..tx+32

  const u16* t1 = t + (size_t)(b*170 + j) * PL;
  const u16* t2 = t + (size_t)(b*170 + 85 + j) * PL;
  // stage halo: 12 rows x 6 aligned chunks x 2 planes = 144 vector loads
  if (tid < 144) {
    int pl = tid / 72, slot = tid % 72;
    int r = slot / 6, ch = slot % 6;
    int gy = ty + r - 2, gxb = tx - 8 + ch*8;
    ushort8 v = {0,0,0,0,0,0,0,0};
    if (gy>=0 && gy<256 && gxb>=0 && gxb<=248)
      v = *reinterpret_cast<const ushort8*>((pl ? t2 : t1) + gy*256 + gxb);
    float* dst = pl ? &s2[r][ch*8] : &s1[r][ch*8];
    #pragma unroll
    for (int q=0;q<8;++q) dst[q] = bf2f((u16)v[q]);
  }
  __syncthreads();
  const float* k0a = wdw + hc*9;
  const float* k0b = wdw + (170+hc)*9;
  #pragma unroll
  for (int i = 0; i < 2; ++i) {
    int idx = tid + i*256;
    if (idx < 340) {
      int r = idx / 34, c = idx % 34;
      int gy = ty + r - 1, gx = tx + c - 1;
      float a = 0.f, bb = 0.f;
      if (gy>=0 && gy<256 && gx>=0 && gx<256) {
        #pragma unroll
        for (int ii=0;ii<3;++ii)
          #pragma unroll
          for (int jj=0;jj<3;++jj) {
            a  += k0a[ii*3+jj]*s1[r+ii][c+6+jj];
            bb += k0b[ii*3+jj]*s2[r+ii][c+6+jj];
          }
      }
      d1s[r][c] = a; d2s[r][c] = bb;
    }
  }
  __syncthreads();
  int ly = tid >> 5, lx = tid & 31;
  const float* k1 = wdw1 + hc*9;
  const float* k2 = wdw2 + hc*9;
  float c2a = 0.f, c2b = 0.f;
  #pragma unroll
  for (int ii=0;ii<3;++ii)
    #pragma unroll
    for (int jj=0;jj<3;++jj) {
      c2a += k1[ii*3+jj]*d1s[ly+ii][lx+jj];
      c2b += k2[ii*3+jj]*d2s[ly+ii][lx+jj];
    }
  float d1c = d1s[ly+1][lx+1], d2c = d2s[ly+1][lx+1];
  float pv = (fast_tanh(c2a) + d1c) * (fast_tanh(c2b) + d2c);
  P[((size_t)(b*170 + hcbase + j))*PL + (ty+ly)*256 + tx + lx] = f2bf(pv);
}

// ---------- IEL out-GEMM: out[b][o][px] += Wh[o][:] . P[b][:][px], K=170 pad 192 ----------
__global__ __launch_bounds__(256) void iel_gemm(
    const u16* __restrict__ Wh, const u16* __restrict__ P,
    float* __restrict__ out) {
  int b  = blockIdx.y;
  int p0 = blockIdx.x * 256;
  int tid = threadIdx.x;
  int lane = tid & 63, wv = tid >> 6;
  int col = lane & 15, kg = lane >> 4;
  int n0 = wv * 64;
  __shared__ u16 shP[256][36];
  f32x4 acc[4][4];
  #pragma unroll
  for (int mt=0;mt<4;++mt)
    #pragma unroll
    for (int nt=0;nt<4;++nt) acc[mt][nt] = (f32x4){0.f,0.f,0.f,0.f};

  int kk = tid & 31, q = tid >> 5;
  for (int c = 0; c < 6; ++c) {
    int hcl = c*32 + kk;
    ushort8 v[4];
    if (hcl < 170) {
      const u16* src = P + (size_t)(b*170 + hcl)*PL + p0 + q*32;
      #pragma unroll
      for (int jj=0;jj<4;++jj) v[jj] = *reinterpret_cast<const ushort8*>(src + jj*8);
    } else {
      #pragma unroll
      for (int jj=0;jj<4;++jj) v[jj] = (ushort8){0,0,0,0,0,0,0,0};
    }
    __syncthreads();            // previous chunk's MFMA reads complete
    #pragma unroll
    for (int jj=0;jj<4;++jj)
      #pragma unroll
      for (int i=0;i<8;++i) shP[q*32 + jj*8 + i][kk] = v[jj][i];
    __syncthreads();
    #pragma unroll
    for (int nt = 0; nt < 4; ++nt) {
      int px = n0 + nt*16 + col;
      const bf16x4* pp = reinterpret_cast<const bf16x4*>(&shP[px][kg*8]);
      bf16x4 plo = pp[0], phi = pp[1];
      bf16x8 bfrag;
      #pragma unroll
      for (int jj=0;jj<4;++jj){ bfrag[jj]=plo[jj]; bfrag[4+jj]=phi[jj]; }
      #pragma unroll
      for (int mt = 0; mt < 4; ++mt) {
        bf16x8 a = *reinterpret_cast<const bf16x8*>(&Wh[(mt*16+col)*192 + c*32 + kg*8]);
        acc[mt][nt] = __builtin_amdgcn_mfma_f32_16x16x32_bf16(a, bfrag, acc[mt][nt], 0,0,0);
      }
    }
  }
  #pragma unroll
  for (int mt=0; mt<4; ++mt)
    #pragma unroll
    for (int nt=0; nt<4; ++nt)
      #pragma unroll
      for (int r=0; r<4; ++r){
        int o = mt*16 + kg*4 + r;
        size_t idx = ((size_t)(b*64 + o))*PL + p0 + n0 + nt*16 + col;
        out[idx] += acc[mt][nt][r];
      }
}

extern "C" void kernel_launch(void* const* d_in, const int* in_sizes, int n_in,
                              void* d_out, int out_size, void* d_ws, size_t ws_size,
                              hipStream_t stream) {
  const float* x      = (const float*)d_in[0];
  const float* y      = (const float*)d_in[1];
  const float* lnw    = (const float*)d_in[2];
  const float* lnb    = (const float*)d_in[3];
  const float* temp   = (const float*)d_in[4];
  const float* wq     = (const float*)d_in[5];
  const float* wq_dw  = (const float*)d_in[6];
  const float* wkv    = (const float*)d_in[7];
  const float* wkv_dw = (const float*)d_in[8];
  const float* wproj  = (const float*)d_in[9];
  const float* w_in   = (const float*)d_in[10];
  const float* w_dw   = (const float*)d_in[11];
  const float* w_dw1  = (const float*)d_in[12];
  const float* w_dw2  = (const float*)d_in[13];
  const float* w_out  = (const float*)d_in[14];

  // ---- arena: 128KB weight head + 178.26MB data = 178.4 MB peak (proven-safe) ----
  char* base = (char*)d_ws;
  u16* Wq_b    = (u16*)(base + 0);        //  8,192 B
  u16* Wkv_b   = (u16*)(base + 8192);     // 16,384 B
  u16* Wp0     = (u16*)(base + 24576);    // 22,528 B
  u16* Wp1     = (u16*)(base + 47104);    // 22,528 B
  u16* Wproj_b = (u16*)(base + 69632);    //  8,192 B
  u16* Wh      = (u16*)(base + 77824);    // 24,576 B (ends 102,400)
  char* A = base + 131072;                // 178,257,920 B data region

  // CAB phase
  u16*  kvpre = (u16*)A;                  // 67,108,864 B [b][128][PL]
  u16*  kvd   = (u16*)(A + 89128960);     // 67,108,864 B (ends 156,237,824)
  u16*  qpre  = (u16*)A;                  // 33,554,432 B (kvpre dead)
  u16*  qd    = (u16*)(A + 33554432);     // 33,554,432 B (ends 67,108,864)
  float* part = (float*)A;                // 655,360 B (qpre dead)
  float* red  = (float*)(A + 1048576);
  float* attnb= (float*)(A + 1572864);
  u16*  o_pm  = (u16*)(A + 4194304);      // 33,554,432 B (ends 37,748,736; qd dead)
  // IEL phase (all CAB scratch dead)
  u16*  tbuf  = (u16*)A;                  // 89,128,960 B [b][170][PL]
  u16*  Pbuf  = (u16*)(A + 89128960);     // 89,128,960 B [b][170][PL] (ends 178,257,920)
  float* xmid = (float*)d_out;

  convert_w<<<64, 256, 0, stream>>>(wq, wkv, w_in, w_out, wproj,
                                    Wq_b, Wkv_b, Wp0, Wp1, Wproj_b, Wh);

  // ---- CAB ----
  ln_gemm<<<dim3(256,4), 256, 0, stream>>>(y, lnw, lnb, Wkv_b, kvpre, 8, 128);
  dwconv3v<<<dim3(32,512), 256, 0, stream>>>(kvpre, wkv_dw, kvd, 128);
  ln_gemm<<<dim3(256,4), 256, 0, stream>>>(x, lnw, lnb, Wq_b, qpre, 4, 64);
  dwconv3v<<<dim3(32,256), 256, 0, stream>>>(qpre, wq_dw, qd, 64);
  attn_reduce1<<<dim3(64,32), 256, 0, stream>>>((const bf16*)qd, (const bf16*)kvd, part);
  attn_reduce2<<<32, 128, 0, stream>>>(part, red);
  attn_softmax<<<1, 64, 0, stream>>>(red, temp, attnb);
  attn_pv<<<1024, 256, 0, stream>>>((const bf16*)kvd, attnb, o_pm);
  gemm_proj<<<dim3(256,4), 256, 0, stream>>>(Wproj_b, o_pm, x, xmid);

  // ---- IEL: two half passes into full P, one K=192 GEMM + residual ----
  ln_gemm<<<dim3(256,4), 256, 0, stream>>>(xmid, lnw, lnb, Wp0, tbuf, 11, 170);
  iel_gate<<<dim3(256,340), 256, 0, stream>>>(tbuf, w_dw, w_dw1, w_dw2, Pbuf, 0);
  ln_gemm<<<dim3(256,4), 256, 0, stream>>>(xmid, lnw, lnb, Wp1, tbuf, 11, 170);
  iel_gate<<<dim3(256,340), 256, 0, stream>>>(tbuf, w_dw, w_dw1, w_dw2, Pbuf, 85);
  iel_gemm<<<dim3(256,4), 256, 0, stream>>>(Wh, Pbuf, xmid);
}

// Round 8
// 543.525 us; speedup vs baseline: 6.1185x; 1.0510x over previous
//
#include <hip/hip_runtime.h>
#include <hip/hip_bf16.h>

typedef __hip_bfloat16 bf16;
typedef unsigned short u16;
typedef __attribute__((ext_vector_type(8))) unsigned short ushort8;
typedef __attribute__((ext_vector_type(8))) short bf16x8;
typedef __attribute__((ext_vector_type(4))) short bf16x4;
typedef __attribute__((ext_vector_type(4))) float f32x4;

#define PL 65536          // H*W
#define EPS_LN 1e-6f

__device__ __forceinline__ float fast_tanh(float v){
  float e = __expf(2.f*v);
  return 1.f - 2.f/(e+1.f);
}
__device__ __forceinline__ u16 f2bf(float f){
  bf16 h = __float2bfloat16(f);
  return __builtin_bit_cast(u16, h);
}
__device__ __forceinline__ float bf2f(u16 v){
  unsigned int u = ((unsigned int)v) << 16;
  return __builtin_bit_cast(float, u);
}

// ---------- pack weights to bf16 with padding / reorder ----------
__global__ void convert_w(const float* __restrict__ wq, const float* __restrict__ wkv,
                          const float* __restrict__ win, const float* __restrict__ wout,
                          const float* __restrict__ wproj,
                          u16* __restrict__ Wq, u16* __restrict__ Wkv,
                          u16* __restrict__ Wp0, u16* __restrict__ Wp1,
                          u16* __restrict__ Wproj, u16* __restrict__ Wh){
  int stride = gridDim.x * 256;
  int gid = blockIdx.x * 256 + threadIdx.x;
  for (int i = gid; i < 64*64;  i += stride) Wq[i]  = f2bf(wq[i]);
  for (int i = gid; i < 128*64; i += stride) Wkv[i] = f2bf(wkv[i]);
  for (int i = gid; i < 176*64; i += stride) {
    int r = i >> 6, c = i & 63;
    // half0 rows: 0..84 -> win[r] (t1_j), 85..169 -> win[170+(r-85)] (t2_j)
    Wp0[i] = (r < 85) ? f2bf(win[r*64+c]) : ((r < 170) ? f2bf(win[(85+r)*64+c]) : 0);
    // half1 rows: 0..84 -> win[85+r], 85..169 -> win[255+(r-85)]
    Wp1[i] = (r < 85) ? f2bf(win[(85+r)*64+c]) : ((r < 170) ? f2bf(win[(170+r)*64+c]) : 0);
  }
  for (int i = gid; i < 64*64; i += stride) Wproj[i] = f2bf(wproj[i]);
  for (int i = gid; i < 64*192; i += stride) {
    int o = i / 192, c = i % 192;
    Wh[i] = (c < 170) ? f2bf(wout[o*170 + c]) : 0;
  }
}

// ---------- fused LN (64ch) + MFMA GEMM: out[b][m][p] = W[m][:] . LN(x)[p][:] ----------
__global__ __launch_bounds__(256) void ln_gemm(
    const float* __restrict__ x, const float* __restrict__ lnw,
    const float* __restrict__ lnb, const u16* __restrict__ W,
    u16* __restrict__ out, int MT, int Mvalid) {
  int b  = blockIdx.y;
  int p0 = blockIdx.x * 256;
  int tid = threadIdx.x;
  int lane = tid & 63, wv = tid >> 6;
  __shared__ u16 shX[256][72];
  {
    const float* xb = x + ((size_t)b * 64) * PL + p0 + tid;
    float xn[64];
    float mu = 0.f;
    #pragma unroll
    for (int c = 0; c < 64; ++c) { xn[c] = xb[(size_t)c * PL]; mu += xn[c]; }
    mu *= (1.f/64.f);
    float var = 0.f;
    #pragma unroll
    for (int c = 0; c < 64; ++c) { float d = xn[c]-mu; var += d*d; }
    var *= (1.f/64.f);
    float inv = rsqrtf(var + EPS_LN);
    #pragma unroll
    for (int c8 = 0; c8 < 8; ++c8) {
      ushort8 pk;
      #pragma unroll
      for (int j = 0; j < 8; ++j)
        pk[j] = f2bf((xn[c8*8+j]-mu)*inv*lnw[c8*8+j] + lnb[c8*8+j]);
      *reinterpret_cast<ushort8*>(&shX[tid][c8*8]) = pk;
    }
  }
  __syncthreads();
  int col = lane & 15, kg = lane >> 4;
  int n0 = wv * 64;
  bf16x8 bfr[4][2];
  #pragma unroll
  for (int nt = 0; nt < 4; ++nt)
    #pragma unroll
    for (int kh = 0; kh < 2; ++kh)
      bfr[nt][kh] = *reinterpret_cast<const bf16x8*>(&shX[n0 + nt*16 + col][kh*32 + kg*8]);
  for (int mt = 0; mt < MT; ++mt) {
    bf16x8 a0 = *reinterpret_cast<const bf16x8*>(&W[(mt*16+col)*64      + kg*8]);
    bf16x8 a1 = *reinterpret_cast<const bf16x8*>(&W[(mt*16+col)*64 + 32 + kg*8]);
    #pragma unroll
    for (int nt = 0; nt < 4; ++nt) {
      f32x4 acc = {0.f,0.f,0.f,0.f};
      acc = __builtin_amdgcn_mfma_f32_16x16x32_bf16(a0, bfr[nt][0], acc, 0,0,0);
      acc = __builtin_amdgcn_mfma_f32_16x16x32_bf16(a1, bfr[nt][1], acc, 0,0,0);
      int mbase = mt*16 + kg*4;
      #pragma unroll
      for (int r = 0; r < 4; ++r) {
        int ch = mbase + r;
        if (ch < Mvalid)
          out[((size_t)b*Mvalid + ch)*PL + p0 + n0 + nt*16 + col] = f2bf(acc[r]);
      }
    }
  }
}

// ---------- vectorized depthwise 3x3, SAME zero pad: 8-row x 256-col tile ----------
__global__ __launch_bounds__(256) void dwconv3v(
    const u16* __restrict__ in, const float* __restrict__ w9,
    u16* __restrict__ out, int C) {
  int plane = blockIdx.y;               // 0..B*C-1
  int cch = plane % C;
  int y0 = blockIdx.x * 8;              // 32 tiles
  int tid = threadIdx.x;
  const u16* ip = in + (size_t)plane * PL;
  __shared__ u16 sh[10][272];           // rows y0-1..y0+8; image col g at LDS col g+8
  #pragma unroll
  for (int i = 0; i < 2; ++i) {
    int idx = tid + i*256;
    if (idx < 320) {
      int r = idx >> 5, seg = idx & 31;
      int gy = y0 - 1 + r;
      ushort8 v = {0,0,0,0,0,0,0,0};
      if (gy >= 0 && gy < 256)
        v = *reinterpret_cast<const ushort8*>(ip + gy*256 + seg*8);
      *reinterpret_cast<ushort8*>(&sh[r][8 + seg*8]) = v;
    }
  }
  if (tid < 10) { sh[tid][7] = 0; sh[tid][264] = 0; }
  __syncthreads();
  float wk[9];
  #pragma unroll
  for (int i=0;i<9;++i) wk[i] = w9[cch*9+i];
  int lr = tid >> 5, xs = (tid & 31) * 8;
  float row[3][10];
  #pragma unroll
  for (int i = 0; i < 3; ++i) {
    ushort8 m = *reinterpret_cast<const ushort8*>(&sh[lr+i][8+xs]);
    row[i][0] = bf2f(sh[lr+i][7+xs]);
    #pragma unroll
    for (int j=0;j<8;++j) row[i][1+j] = bf2f((u16)m[j]);
    row[i][9] = bf2f(sh[lr+i][16+xs]);
  }
  ushort8 o;
  #pragma unroll
  for (int j = 0; j < 8; ++j) {
    float a = 0.f;
    #pragma unroll
    for (int i=0;i<3;++i)
      #pragma unroll
      for (int k=0;k<3;++k) a += wk[i*3+k]*row[i][j+k];
    o[j] = f2bf(a);
  }
  int gy = y0 + lr;
  *reinterpret_cast<ushort8*>(out + (size_t)plane*PL + gy*256 + xs) = o;
}

// ---------- stage-1 reduction: per (b,h) Gram(8x8) + sumsq(q),sumsq(k) ----------
__global__ __launch_bounds__(256) void attn_reduce1(
    const bf16* __restrict__ q, const bf16* __restrict__ kv,
    float* __restrict__ part) {
  int bh = blockIdx.y;
  int b = bh >> 3, h = bh & 7;
  int s = blockIdx.x;
  int t = threadIdx.x;
  const bf16* qb = q  + ((size_t)b*64  + h*8) * PL;
  const bf16* kb = kv + ((size_t)b*128 + h*8) * PL;
  float acc[80];
  #pragma unroll
  for (int i=0;i<80;++i) acc[i]=0.f;
  for (int r = 0; r < 4; ++r) {
    int p = s*1024 + r*256 + t;
    float qv[8], kvv[8];
    #pragma unroll
    for (int c=0;c<8;++c) {
      qv[c]=__bfloat162float(qb[(size_t)c*PL+p]);
      kvv[c]=__bfloat162float(kb[(size_t)c*PL+p]);
    }
    #pragma unroll
    for (int c=0;c<8;++c)
      #pragma unroll
      for (int d=0;d<8;++d) acc[c*8+d] += qv[c]*kvv[d];
    #pragma unroll
    for (int c=0;c<8;++c) { acc[64+c] += qv[c]*qv[c]; acc[72+c] += kvv[c]*kvv[c]; }
  }
  __shared__ float lds[4][80];
  int lane = t & 63, wv = t >> 6;
  #pragma unroll
  for (int i=0;i<80;++i) {
    float v = acc[i];
    for (int off=32; off; off>>=1) v += __shfl_down(v, off);
    if (lane==0) lds[wv][i]=v;
  }
  __syncthreads();
  if (t < 80)
    part[((size_t)bh*64 + s)*80 + t] = lds[0][t]+lds[1][t]+lds[2][t]+lds[3][t];
}

__global__ void attn_reduce2(const float* __restrict__ part, float* __restrict__ red) {
  int bh = blockIdx.x; int t = threadIdx.x;
  if (t < 80) {
    float v = 0.f;
    for (int s=0;s<64;++s) v += part[((size_t)bh*64+s)*80+t];
    red[bh*80+t]=v;
  }
}

__global__ void attn_softmax(const float* __restrict__ red, const float* __restrict__ temp,
                             float* __restrict__ attn) {
  int bh = threadIdx.x;
  if (bh >= 32) return;
  int h = bh & 7;
  const float* r = red + bh*80;
  float nq[8], nk[8];
  for (int c=0;c<8;++c) nq[c] = fmaxf(sqrtf(r[64+c]), 1e-12f);
  for (int d=0;d<8;++d) nk[d] = fmaxf(sqrtf(r[72+d]), 1e-12f);
  float tm = temp[h];
  for (int c=0;c<8;++c) {
    float a[8]; float m=-1e30f;
    for (int d=0;d<8;++d){ a[d] = r[c*8+d]/(nq[c]*nk[d]) * tm; m=fmaxf(m,a[d]); }
    float ss=0.f;
    for (int d=0;d<8;++d){ a[d]=__expf(a[d]-m); ss+=a[d]; }
    float inv=1.f/ss;
    for (int d=0;d<8;++d) attn[bh*64 + c*8 + d] = a[d]*inv;
  }
}

// ---------- PV only -> o pixel-major bf16 [b][PL][64] ----------
__global__ __launch_bounds__(256) void attn_pv(
    const bf16* __restrict__ kv, const float* __restrict__ attnb,
    u16* __restrict__ o_pm) {
  int p = blockIdx.x * 256 + threadIdx.x;
  int b = p >> 16, pix = p & 65535;
  __shared__ float at[512];
  for (int i=threadIdx.x; i<512; i+=256) at[i]=attnb[b*512+i];
  __syncthreads();
  const bf16* vb = kv + ((size_t)b*128 + 64)*PL + pix;
  u16* ob = o_pm + ((size_t)b*PL + pix)*64;
  #pragma unroll
  for (int h=0;h<8;++h){
    float vv[8];
    #pragma unroll
    for (int d=0;d<8;++d) vv[d]=__bfloat162float(vb[(size_t)(h*8+d)*PL]);
    ushort8 pk;
    #pragma unroll
    for (int c=0;c<8;++c){
      float acc=0.f;
      #pragma unroll
      for (int d=0;d<8;++d) acc += at[h*64+c*8+d]*vv[d];
      pk[c] = f2bf(acc);
    }
    *reinterpret_cast<ushort8*>(ob + h*8) = pk;
  }
}

// ---------- MFMA proj: out[b][o][p] = x[b][o][p] + Wp[o][:] . o_pm[p][:] ----------
__global__ __launch_bounds__(256) void gemm_proj(
    const u16* __restrict__ Wp, const u16* __restrict__ o_pm,
    const float* __restrict__ x, float* __restrict__ out) {
  int b  = blockIdx.y;
  int p0 = blockIdx.x * 256;
  int tid = threadIdx.x;
  int lane = tid & 63, wv = tid >> 6;
  __shared__ u16 shX[256][72];
  const u16* src = o_pm + ((size_t)b * PL + p0) * 64;
  #pragma unroll
  for (int c8 = 0; c8 < 8; ++c8)
    *reinterpret_cast<ushort8*>(&shX[tid][c8*8]) =
        *reinterpret_cast<const ushort8*>(src + (size_t)tid*64 + c8*8);
  __syncthreads();
  int col = lane & 15, kg = lane >> 4;
  int n0 = wv * 64;
  bf16x8 bfr[4][2];
  #pragma unroll
  for (int nt = 0; nt < 4; ++nt)
    #pragma unroll
    for (int kh = 0; kh < 2; ++kh)
      bfr[nt][kh] = *reinterpret_cast<const bf16x8*>(&shX[n0 + nt*16 + col][kh*32 + kg*8]);
  #pragma unroll
  for (int mt = 0; mt < 4; ++mt) {
    bf16x8 a0 = *reinterpret_cast<const bf16x8*>(&Wp[(mt*16+col)*64      + kg*8]);
    bf16x8 a1 = *reinterpret_cast<const bf16x8*>(&Wp[(mt*16+col)*64 + 32 + kg*8]);
    #pragma unroll
    for (int nt = 0; nt < 4; ++nt) {
      f32x4 acc = {0.f,0.f,0.f,0.f};
      acc = __builtin_amdgcn_mfma_f32_16x16x32_bf16(a0, bfr[nt][0], acc, 0,0,0);
      acc = __builtin_amdgcn_mfma_f32_16x16x32_bf16(a1, bfr[nt][1], acc, 0,0,0);
      #pragma unroll
      for (int r = 0; r < 4; ++r) {
        int o = mt*16 + kg*4 + r;
        size_t idx = ((size_t)(b*64 + o))*PL + p0 + n0 + nt*16 + col;
        out[idx] = x[idx] + acc[r];
      }
    }
  }
}

// ---------- IEL gate v2: 32x64 tile, 8 outputs/thread, vectorized LDS stencils ----------
// t: [b][170][PL] (planes 0..84 = t1_j, 85..169 = t2_j for this half)
// P: [b][170][PL], this half writes planes hcbase..hcbase+84
__global__ __launch_bounds__(256) void iel_gate2(
    const u16* __restrict__ t, const float* __restrict__ wdw,
    const float* __restrict__ wdw1, const float* __restrict__ wdw2,
    u16* __restrict__ P, int hcbase) {
  int pj = blockIdx.y;                  // 0..B*85-1
  int b = pj / 85, j = pj % 85;
  int hc = hcbase + j;
  int bx = blockIdx.x;                  // 0..31: 8 y-tiles x 4 x-tiles
  int y0 = (bx >> 2) * 32;
  int x0 = (bx & 3) * 64;
  int tid = threadIdx.x;

  __shared__ float sT[2][36][84];   // t planes; row = gy-(y0-2); col = gx-(x0-8)
  __shared__ float sD[2][34][76];   // d planes; row = gy-(y0-1); col = (gx-x0)+4

  const u16* t1 = t + (size_t)(b*170 + j) * PL;
  const u16* t2 = t + (size_t)(b*170 + 85 + j) * PL;

  // ---- stage t halo as f32: 2 planes x 36 rows x 10 aligned chunks ----
  #pragma unroll
  for (int it = 0; it < 3; ++it) {
    int idx = tid + it*256;
    if (idx < 720) {
      int pl = idx / 360, rem = idx % 360;
      int r = rem / 10, ch = rem % 10;
      int gy = y0 + r - 2;
      int gxb = x0 - 8 + ch*8;
      ushort8 v = {0,0,0,0,0,0,0,0};
      if (gy >= 0 && gy < 256 && gxb >= 0 && gxb <= 248)
        v = *reinterpret_cast<const ushort8*>((pl ? t2 : t1) + gy*256 + gxb);
      f32x4 f0 = { bf2f((u16)v[0]), bf2f((u16)v[1]), bf2f((u16)v[2]), bf2f((u16)v[3]) };
      f32x4 f1 = { bf2f((u16)v[4]), bf2f((u16)v[5]), bf2f((u16)v[6]), bf2f((u16)v[7]) };
      float* dst = pl ? &sT[1][r][ch*8] : &sT[0][r][ch*8];
      *reinterpret_cast<f32x4*>(dst)     = f0;
      *reinterpret_cast<f32x4*>(dst + 4) = f1;
    }
  }
  __syncthreads();

  // ---- d = conv3(t), zeroed outside image: 2 planes x 34 rows x 9 segs of 8 ----
  #pragma unroll
  for (int it = 0; it < 3; ++it) {
    int idx = tid + it*256;
    if (idx < 612) {
      int pl = idx / 306, rem = idx % 306;
      int r = rem / 9, si = rem % 9;          // d row rel y = r-1; seg cols rel x = si*8-4 ..+7
      int gy = y0 + r - 1;
      float w[3][16];
      #pragma unroll
      for (int i = 0; i < 3; ++i)
        #pragma unroll
        for (int k = 0; k < 4; ++k) {
          f32x4 q = *reinterpret_cast<const f32x4*>(&sT[pl][r+i][si*8 + 4*k]);
          w[i][4*k+0]=q[0]; w[i][4*k+1]=q[1]; w[i][4*k+2]=q[2]; w[i][4*k+3]=q[3];
        }
      const float* kp = wdw + (pl ? (170+hc) : hc)*9;
      float kk[9];
      #pragma unroll
      for (int i=0;i<9;++i) kk[i] = kp[i];
      int gx0 = x0 + si*8 - 4;
      bool rowok = (gy >= 0 && gy < 256);
      f32x4 o0, o1;
      #pragma unroll
      for (int jj = 0; jj < 8; ++jj) {
        float a = 0.f;
        #pragma unroll
        for (int i=0;i<3;++i)
          #pragma unroll
          for (int dk=0;dk<3;++dk)
            a += kk[i*3+dk] * w[i][jj+dk+3];
        int gx = gx0 + jj;
        bool ok = rowok && gx >= 0 && gx < 256;
        float dv = ok ? a : 0.f;
        if (jj < 4) o0[jj] = dv; else o1[jj-4] = dv;
      }
      float* dst = pl ? &sD[1][r][si*8] : &sD[0][r][si*8];
      *reinterpret_cast<f32x4*>(dst)     = o0;
      *reinterpret_cast<f32x4*>(dst + 4) = o1;
    }
  }
  __syncthreads();

  // ---- second conv + tanh gate, 8 outputs per thread ----
  int ry = tid >> 3, seg = tid & 7;     // output row ry (0..31), cols x0+seg*8..+7
  float x1[8], x2[8];
  #pragma unroll
  for (int pl = 0; pl < 2; ++pl) {
    float w[3][16];
    #pragma unroll
    for (int i = 0; i < 3; ++i)
      #pragma unroll
      for (int k = 0; k < 4; ++k) {
        f32x4 q = *reinterpret_cast<const f32x4*>(&sD[pl][ry+i][seg*8 + 4*k]);
        w[i][4*k+0]=q[0]; w[i][4*k+1]=q[1]; w[i][4*k+2]=q[2]; w[i][4*k+3]=q[3];
      }
    const float* kp = (pl ? wdw2 : wdw1) + hc*9;
    float kk[9];
    #pragma unroll
    for (int i=0;i<9;++i) kk[i] = kp[i];
    #pragma unroll
    for (int jj = 0; jj < 8; ++jj) {
      float a = 0.f;
      #pragma unroll
      for (int i=0;i<3;++i)
        #pragma unroll
        for (int dk=0;dk<3;++dk)
          a += kk[i*3+dk] * w[i][jj+dk+3];
      float dc = w[1][jj+4];
      float g = fast_tanh(a) + dc;
      if (pl) x2[jj] = g; else x1[jj] = g;
    }
  }
  ushort8 o;
  #pragma unroll
  for (int jj = 0; jj < 8; ++jj) o[jj] = f2bf(x1[jj]*x2[jj]);
  int gy = y0 + ry;
  *reinterpret_cast<ushort8*>(
      P + ((size_t)(b*170 + hcbase + j))*PL + gy*256 + x0 + seg*8) = o;
}

// ---------- IEL out-GEMM: out[b][o][px] += Wh[o][:] . P[b][:][px], K=170 pad 192 ----------
__global__ __launch_bounds__(256) void iel_gemm(
    const u16* __restrict__ Wh, const u16* __restrict__ P,
    float* __restrict__ out) {
  int b  = blockIdx.y;
  int p0 = blockIdx.x * 256;
  int tid = threadIdx.x;
  int lane = tid & 63, wv = tid >> 6;
  int col = lane & 15, kg = lane >> 4;
  int n0 = wv * 64;
  __shared__ u16 shP[256][36];
  f32x4 acc[4][4];
  #pragma unroll
  for (int mt=0;mt<4;++mt)
    #pragma unroll
    for (int nt=0;nt<4;++nt) acc[mt][nt] = (f32x4){0.f,0.f,0.f,0.f};

  int kk = tid & 31, q = tid >> 5;
  for (int c = 0; c < 6; ++c) {
    int hcl = c*32 + kk;
    ushort8 v[4];
    if (hcl < 170) {
      const u16* src = P + (size_t)(b*170 + hcl)*PL + p0 + q*32;
      #pragma unroll
      for (int jj=0;jj<4;++jj) v[jj] = *reinterpret_cast<const ushort8*>(src + jj*8);
    } else {
      #pragma unroll
      for (int jj=0;jj<4;++jj) v[jj] = (ushort8){0,0,0,0,0,0,0,0};
    }
    __syncthreads();            // previous chunk's MFMA reads complete
    #pragma unroll
    for (int jj=0;jj<4;++jj)
      #pragma unroll
      for (int i=0;i<8;++i) shP[q*32 + jj*8 + i][kk] = v[jj][i];
    __syncthreads();
    #pragma unroll
    for (int nt = 0; nt < 4; ++nt) {
      int px = n0 + nt*16 + col;
      const bf16x4* pp = reinterpret_cast<const bf16x4*>(&shP[px][kg*8]);
      bf16x4 plo = pp[0], phi = pp[1];
      bf16x8 bfrag;
      #pragma unroll
      for (int jj=0;jj<4;++jj){ bfrag[jj]=plo[jj]; bfrag[4+jj]=phi[jj]; }
      #pragma unroll
      for (int mt = 0; mt < 4; ++mt) {
        bf16x8 a = *reinterpret_cast<const bf16x8*>(&Wh[(mt*16+col)*192 + c*32 + kg*8]);
        acc[mt][nt] = __builtin_amdgcn_mfma_f32_16x16x32_bf16(a, bfrag, acc[mt][nt], 0,0,0);
      }
    }
  }
  #pragma unroll
  for (int mt=0; mt<4; ++mt)
    #pragma unroll
    for (int nt=0; nt<4; ++nt)
      #pragma unroll
      for (int r=0; r<4; ++r){
        int o = mt*16 + kg*4 + r;
        size_t idx = ((size_t)(b*64 + o))*PL + p0 + n0 + nt*16 + col;
        out[idx] += acc[mt][nt][r];
      }
}

extern "C" void kernel_launch(void* const* d_in, const int* in_sizes, int n_in,
                              void* d_out, int out_size, void* d_ws, size_t ws_size,
                              hipStream_t stream) {
  const float* x      = (const float*)d_in[0];
  const float* y      = (const float*)d_in[1];
  const float* lnw    = (const float*)d_in[2];
  const float* lnb    = (const float*)d_in[3];
  const float* temp   = (const float*)d_in[4];
  const float* wq     = (const float*)d_in[5];
  const float* wq_dw  = (const float*)d_in[6];
  const float* wkv    = (const float*)d_in[7];
  const float* wkv_dw = (const float*)d_in[8];
  const float* wproj  = (const float*)d_in[9];
  const float* w_in   = (const float*)d_in[10];
  const float* w_dw   = (const float*)d_in[11];
  const float* w_dw1  = (const float*)d_in[12];
  const float* w_dw2  = (const float*)d_in[13];
  const float* w_out  = (const float*)d_in[14];

  // ---- arena: 128KB weight head + 178.26MB data = 178.4 MB peak (proven-safe) ----
  char* base = (char*)d_ws;
  u16* Wq_b    = (u16*)(base + 0);        //  8,192 B
  u16* Wkv_b   = (u16*)(base + 8192);     // 16,384 B
  u16* Wp0     = (u16*)(base + 24576);    // 22,528 B
  u16* Wp1     = (u16*)(base + 47104);    // 22,528 B
  u16* Wproj_b = (u16*)(base + 69632);    //  8,192 B
  u16* Wh      = (u16*)(base + 77824);    // 24,576 B (ends 102,400)
  char* A = base + 131072;                // 178,257,920 B data region

  // CAB phase
  u16*  kvpre = (u16*)A;                  // 67,108,864 B [b][128][PL]
  u16*  kvd   = (u16*)(A + 89128960);     // 67,108,864 B (ends 156,237,824)
  u16*  qpre  = (u16*)A;                  // 33,554,432 B (kvpre dead)
  u16*  qd    = (u16*)(A + 33554432);     // 33,554,432 B (ends 67,108,864)
  float* part = (float*)A;                // 655,360 B (qpre dead)
  float* red  = (float*)(A + 1048576);
  float* attnb= (float*)(A + 1572864);
  u16*  o_pm  = (u16*)(A + 4194304);      // 33,554,432 B (ends 37,748,736; qd dead)
  // IEL phase (all CAB scratch dead)
  u16*  tbuf  = (u16*)A;                  // 89,128,960 B [b][170][PL]
  u16*  Pbuf  = (u16*)(A + 89128960);     // 89,128,960 B [b][170][PL] (ends 178,257,920)
  float* xmid = (float*)d_out;

  convert_w<<<64, 256, 0, stream>>>(wq, wkv, w_in, w_out, wproj,
                                    Wq_b, Wkv_b, Wp0, Wp1, Wproj_b, Wh);

  // ---- CAB ----
  ln_gemm<<<dim3(256,4), 256, 0, stream>>>(y, lnw, lnb, Wkv_b, kvpre, 8, 128);
  dwconv3v<<<dim3(32,512), 256, 0, stream>>>(kvpre, wkv_dw, kvd, 128);
  ln_gemm<<<dim3(256,4), 256, 0, stream>>>(x, lnw, lnb, Wq_b, qpre, 4, 64);
  dwconv3v<<<dim3(32,256), 256, 0, stream>>>(qpre, wq_dw, qd, 64);
  attn_reduce1<<<dim3(64,32), 256, 0, stream>>>((const bf16*)qd, (const bf16*)kvd, part);
  attn_reduce2<<<32, 128, 0, stream>>>(part, red);
  attn_softmax<<<1, 64, 0, stream>>>(red, temp, attnb);
  attn_pv<<<1024, 256, 0, stream>>>((const bf16*)kvd, attnb, o_pm);
  gemm_proj<<<dim3(256,4), 256, 0, stream>>>(Wproj_b, o_pm, x, xmid);

  // ---- IEL: two half passes into full P, one K=192 GEMM + residual ----
  ln_gemm<<<dim3(256,4), 256, 0, stream>>>(xmid, lnw, lnb, Wp0, tbuf, 11, 170);
  iel_gate2<<<dim3(32,340), 256, 0, stream>>>(tbuf, w_dw, w_dw1, w_dw2, Pbuf, 0);
  ln_gemm<<<dim3(256,4), 256, 0, stream>>>(xmid, lnw, lnb, Wp1, tbuf, 11, 170);
  iel_gate2<<<dim3(32,340), 256, 0, stream>>>(tbuf, w_dw, w_dw1, w_dw2, Pbuf, 85);
  iel_gemm<<<dim3(256,4), 256, 0, stream>>>(Wh, Pbuf, xmid);
}

// Round 9
// 516.807 us; speedup vs baseline: 6.4348x; 1.0517x over previous
//
#include <hip/hip_runtime.h>
#include <hip/hip_bf16.h>

typedef __hip_bfloat16 bf16;
typedef unsigned short u16;
typedef __attribute__((ext_vector_type(8))) unsigned short ushort8;
typedef __attribute__((ext_vector_type(8))) short bf16x8;
typedef __attribute__((ext_vector_type(4))) short bf16x4;
typedef __attribute__((ext_vector_type(4))) float f32x4;

#define PL 65536          // H*W
#define EPS_LN 1e-6f

__device__ __forceinline__ float fast_tanh(float v){
  float e = __expf(2.f*v);
  return 1.f - 2.f/(e+1.f);
}
__device__ __forceinline__ u16 f2bf(float f){
  bf16 h = __float2bfloat16(f);
  return __builtin_bit_cast(u16, h);
}
__device__ __forceinline__ float bf2f(u16 v){
  unsigned int u = ((unsigned int)v) << 16;
  return __builtin_bit_cast(float, u);
}

// ---------- pack weights to bf16 with padding / reorder ----------
__global__ void convert_w(const float* __restrict__ wq, const float* __restrict__ wkv,
                          const float* __restrict__ win, const float* __restrict__ wout,
                          const float* __restrict__ wproj,
                          u16* __restrict__ Wq, u16* __restrict__ Wkv,
                          u16* __restrict__ Wp0, u16* __restrict__ Wp1,
                          u16* __restrict__ Wproj, u16* __restrict__ Wh){
  int stride = gridDim.x * 256;
  int gid = blockIdx.x * 256 + threadIdx.x;
  for (int i = gid; i < 64*64;  i += stride) Wq[i]  = f2bf(wq[i]);
  for (int i = gid; i < 128*64; i += stride) Wkv[i] = f2bf(wkv[i]);
  for (int i = gid; i < 176*64; i += stride) {
    int r = i >> 6, c = i & 63;
    // half0 rows: 0..84 -> win[r] (t1_j), 85..169 -> win[170+(r-85)] (t2_j)
    Wp0[i] = (r < 85) ? f2bf(win[r*64+c]) : ((r < 170) ? f2bf(win[(85+r)*64+c]) : 0);
    // half1 rows: 0..84 -> win[85+r], 85..169 -> win[255+(r-85)]
    Wp1[i] = (r < 85) ? f2bf(win[(85+r)*64+c]) : ((r < 170) ? f2bf(win[(170+r)*64+c]) : 0);
  }
  for (int i = gid; i < 64*64; i += stride) Wproj[i] = f2bf(wproj[i]);
  for (int i = gid; i < 64*192; i += stride) {
    int o = i / 192, c = i % 192;
    Wh[i] = (c < 170) ? f2bf(wout[o*170 + c]) : 0;
  }
}

// ---------- fused LN (64ch) + MFMA GEMM: out[b][m][p] = W[m][:] . LN(x)[p][:] ----------
__global__ __launch_bounds__(256) void ln_gemm(
    const float* __restrict__ x, const float* __restrict__ lnw,
    const float* __restrict__ lnb, const u16* __restrict__ W,
    u16* __restrict__ out, int MT, int Mvalid) {
  int b  = blockIdx.y;
  int p0 = blockIdx.x * 256;
  int tid = threadIdx.x;
  int lane = tid & 63, wv = tid >> 6;
  __shared__ u16 shX[256][72];
  {
    const float* xb = x + ((size_t)b * 64) * PL + p0 + tid;
    float xn[64];
    float mu = 0.f;
    #pragma unroll
    for (int c = 0; c < 64; ++c) { xn[c] = xb[(size_t)c * PL]; mu += xn[c]; }
    mu *= (1.f/64.f);
    float var = 0.f;
    #pragma unroll
    for (int c = 0; c < 64; ++c) { float d = xn[c]-mu; var += d*d; }
    var *= (1.f/64.f);
    float inv = rsqrtf(var + EPS_LN);
    #pragma unroll
    for (int c8 = 0; c8 < 8; ++c8) {
      ushort8 pk;
      #pragma unroll
      for (int j = 0; j < 8; ++j)
        pk[j] = f2bf((xn[c8*8+j]-mu)*inv*lnw[c8*8+j] + lnb[c8*8+j]);
      *reinterpret_cast<ushort8*>(&shX[tid][c8*8]) = pk;
    }
  }
  __syncthreads();
  int col = lane & 15, kg = lane >> 4;
  int n0 = wv * 64;
  bf16x8 bfr[4][2];
  #pragma unroll
  for (int nt = 0; nt < 4; ++nt)
    #pragma unroll
    for (int kh = 0; kh < 2; ++kh)
      bfr[nt][kh] = *reinterpret_cast<const bf16x8*>(&shX[n0 + nt*16 + col][kh*32 + kg*8]);
  for (int mt = 0; mt < MT; ++mt) {
    bf16x8 a0 = *reinterpret_cast<const bf16x8*>(&W[(mt*16+col)*64      + kg*8]);
    bf16x8 a1 = *reinterpret_cast<const bf16x8*>(&W[(mt*16+col)*64 + 32 + kg*8]);
    #pragma unroll
    for (int nt = 0; nt < 4; ++nt) {
      f32x4 acc = {0.f,0.f,0.f,0.f};
      acc = __builtin_amdgcn_mfma_f32_16x16x32_bf16(a0, bfr[nt][0], acc, 0,0,0);
      acc = __builtin_amdgcn_mfma_f32_16x16x32_bf16(a1, bfr[nt][1], acc, 0,0,0);
      int mbase = mt*16 + kg*4;
      #pragma unroll
      for (int r = 0; r < 4; ++r) {
        int ch = mbase + r;
        if (ch < Mvalid)
          out[((size_t)b*Mvalid + ch)*PL + p0 + n0 + nt*16 + col] = f2bf(acc[r]);
      }
    }
  }
}

// ---------- vectorized depthwise 3x3, SAME zero pad: 8-row x 256-col tile ----------
__global__ __launch_bounds__(256) void dwconv3v(
    const u16* __restrict__ in, const float* __restrict__ w9,
    u16* __restrict__ out, int C) {
  int plane = blockIdx.y;               // 0..B*C-1
  int cch = plane % C;
  int y0 = blockIdx.x * 8;              // 32 tiles
  int tid = threadIdx.x;
  const u16* ip = in + (size_t)plane * PL;
  __shared__ u16 sh[10][272];           // rows y0-1..y0+8; image col g at LDS col g+8
  #pragma unroll
  for (int i = 0; i < 2; ++i) {
    int idx = tid + i*256;
    if (idx < 320) {
      int r = idx >> 5, seg = idx & 31;
      int gy = y0 - 1 + r;
      ushort8 v = {0,0,0,0,0,0,0,0};
      if (gy >= 0 && gy < 256)
        v = *reinterpret_cast<const ushort8*>(ip + gy*256 + seg*8);
      *reinterpret_cast<ushort8*>(&sh[r][8 + seg*8]) = v;
    }
  }
  if (tid < 10) { sh[tid][7] = 0; sh[tid][264] = 0; }
  __syncthreads();
  float wk[9];
  #pragma unroll
  for (int i=0;i<9;++i) wk[i] = w9[cch*9+i];
  int lr = tid >> 5, xs = (tid & 31) * 8;
  float row[3][10];
  #pragma unroll
  for (int i = 0; i < 3; ++i) {
    ushort8 m = *reinterpret_cast<const ushort8*>(&sh[lr+i][8+xs]);
    row[i][0] = bf2f(sh[lr+i][7+xs]);
    #pragma unroll
    for (int j=0;j<8;++j) row[i][1+j] = bf2f((u16)m[j]);
    row[i][9] = bf2f(sh[lr+i][16+xs]);
  }
  ushort8 o;
  #pragma unroll
  for (int j = 0; j < 8; ++j) {
    float a = 0.f;
    #pragma unroll
    for (int i=0;i<3;++i)
      #pragma unroll
      for (int k=0;k<3;++k) a += wk[i*3+k]*row[i][j+k];
    o[j] = f2bf(a);
  }
  int gy = y0 + lr;
  *reinterpret_cast<ushort8*>(out + (size_t)plane*PL + gy*256 + xs) = o;
}

// ---------- stage-1 reduction: per (b,h) Gram(8x8) + sumsq(q),sumsq(k) ----------
__global__ __launch_bounds__(256) void attn_reduce1(
    const bf16* __restrict__ q, const bf16* __restrict__ kv,
    float* __restrict__ part) {
  int bh = blockIdx.y;
  int b = bh >> 3, h = bh & 7;
  int s = blockIdx.x;
  int t = threadIdx.x;
  const bf16* qb = q  + ((size_t)b*64  + h*8) * PL;
  const bf16* kb = kv + ((size_t)b*128 + h*8) * PL;
  float acc[80];
  #pragma unroll
  for (int i=0;i<80;++i) acc[i]=0.f;
  for (int r = 0; r < 4; ++r) {
    int p = s*1024 + r*256 + t;
    float qv[8], kvv[8];
    #pragma unroll
    for (int c=0;c<8;++c) {
      qv[c]=__bfloat162float(qb[(size_t)c*PL+p]);
      kvv[c]=__bfloat162float(kb[(size_t)c*PL+p]);
    }
    #pragma unroll
    for (int c=0;c<8;++c)
      #pragma unroll
      for (int d=0;d<8;++d) acc[c*8+d] += qv[c]*kvv[d];
    #pragma unroll
    for (int c=0;c<8;++c) { acc[64+c] += qv[c]*qv[c]; acc[72+c] += kvv[c]*kvv[c]; }
  }
  __shared__ float lds[4][80];
  int lane = t & 63, wv = t >> 6;
  #pragma unroll
  for (int i=0;i<80;++i) {
    float v = acc[i];
    for (int off=32; off; off>>=1) v += __shfl_down(v, off);
    if (lane==0) lds[wv][i]=v;
  }
  __syncthreads();
  if (t < 80)
    part[((size_t)bh*64 + s)*80 + t] = lds[0][t]+lds[1][t]+lds[2][t]+lds[3][t];
}

__global__ void attn_reduce2(const float* __restrict__ part, float* __restrict__ red) {
  int bh = blockIdx.x; int t = threadIdx.x;
  if (t < 80) {
    float v = 0.f;
    for (int s=0;s<64;++s) v += part[((size_t)bh*64+s)*80+t];
    red[bh*80+t]=v;
  }
}

__global__ void attn_softmax(const float* __restrict__ red, const float* __restrict__ temp,
                             float* __restrict__ attn) {
  int bh = threadIdx.x;
  if (bh >= 32) return;
  int h = bh & 7;
  const float* r = red + bh*80;
  float nq[8], nk[8];
  for (int c=0;c<8;++c) nq[c] = fmaxf(sqrtf(r[64+c]), 1e-12f);
  for (int d=0;d<8;++d) nk[d] = fmaxf(sqrtf(r[72+d]), 1e-12f);
  float tm = temp[h];
  for (int c=0;c<8;++c) {
    float a[8]; float m=-1e30f;
    for (int d=0;d<8;++d){ a[d] = r[c*8+d]/(nq[c]*nk[d]) * tm; m=fmaxf(m,a[d]); }
    float ss=0.f;
    for (int d=0;d<8;++d){ a[d]=__expf(a[d]-m); ss+=a[d]; }
    float inv=1.f/ss;
    for (int d=0;d<8;++d) attn[bh*64 + c*8 + d] = a[d]*inv;
  }
}

// ---------- PV only -> o pixel-major bf16 [b][PL][64] ----------
__global__ __launch_bounds__(256) void attn_pv(
    const bf16* __restrict__ kv, const float* __restrict__ attnb,
    u16* __restrict__ o_pm) {
  int p = blockIdx.x * 256 + threadIdx.x;
  int b = p >> 16, pix = p & 65535;
  __shared__ float at[512];
  for (int i=threadIdx.x; i<512; i+=256) at[i]=attnb[b*512+i];
  __syncthreads();
  const bf16* vb = kv + ((size_t)b*128 + 64)*PL + pix;
  u16* ob = o_pm + ((size_t)b*PL + pix)*64;
  #pragma unroll
  for (int h=0;h<8;++h){
    float vv[8];
    #pragma unroll
    for (int d=0;d<8;++d) vv[d]=__bfloat162float(vb[(size_t)(h*8+d)*PL]);
    ushort8 pk;
    #pragma unroll
    for (int c=0;c<8;++c){
      float acc=0.f;
      #pragma unroll
      for (int d=0;d<8;++d) acc += at[h*64+c*8+d]*vv[d];
      pk[c] = f2bf(acc);
    }
    *reinterpret_cast<ushort8*>(ob + h*8) = pk;
  }
}

// ---------- MFMA proj: out[b][o][p] = x[b][o][p] + Wp[o][:] . o_pm[p][:] ----------
__global__ __launch_bounds__(256) void gemm_proj(
    const u16* __restrict__ Wp, const u16* __restrict__ o_pm,
    const float* __restrict__ x, float* __restrict__ out) {
  int b  = blockIdx.y;
  int p0 = blockIdx.x * 256;
  int tid = threadIdx.x;
  int lane = tid & 63, wv = tid >> 6;
  __shared__ u16 shX[256][72];
  const u16* src = o_pm + ((size_t)b * PL + p0) * 64;
  #pragma unroll
  for (int c8 = 0; c8 < 8; ++c8)
    *reinterpret_cast<ushort8*>(&shX[tid][c8*8]) =
        *reinterpret_cast<const ushort8*>(src + (size_t)tid*64 + c8*8);
  __syncthreads();
  int col = lane & 15, kg = lane >> 4;
  int n0 = wv * 64;
  bf16x8 bfr[4][2];
  #pragma unroll
  for (int nt = 0; nt < 4; ++nt)
    #pragma unroll
    for (int kh = 0; kh < 2; ++kh)
      bfr[nt][kh] = *reinterpret_cast<const bf16x8*>(&shX[n0 + nt*16 + col][kh*32 + kg*8]);
  #pragma unroll
  for (int mt = 0; mt < 4; ++mt) {
    bf16x8 a0 = *reinterpret_cast<const bf16x8*>(&Wp[(mt*16+col)*64      + kg*8]);
    bf16x8 a1 = *reinterpret_cast<const bf16x8*>(&Wp[(mt*16+col)*64 + 32 + kg*8]);
    #pragma unroll
    for (int nt = 0; nt < 4; ++nt) {
      f32x4 acc = {0.f,0.f,0.f,0.f};
      acc = __builtin_amdgcn_mfma_f32_16x16x32_bf16(a0, bfr[nt][0], acc, 0,0,0);
      acc = __builtin_amdgcn_mfma_f32_16x16x32_bf16(a1, bfr[nt][1], acc, 0,0,0);
      #pragma unroll
      for (int r = 0; r < 4; ++r) {
        int o = mt*16 + kg*4 + r;
        size_t idx = ((size_t)(b*64 + o))*PL + p0 + n0 + nt*16 + col;
        out[idx] = x[idx] + acc[r];
      }
    }
  }
}

// ---------- IEL gate v3: 32x64 tile, bf16 LDS staging (24.6KB), 8 outputs/thread ----------
// t: [b][170][PL] (planes 0..84 = t1_j, 85..169 = t2_j for this half)
// P: [b][170][PL], this half writes planes hcbase..hcbase+84
__global__ __launch_bounds__(256) void iel_gate2(
    const u16* __restrict__ t, const float* __restrict__ wdw,
    const float* __restrict__ wdw1, const float* __restrict__ wdw2,
    u16* __restrict__ P, int hcbase) {
  int pj = blockIdx.y;                  // 0..B*85-1
  int b = pj / 85, j = pj % 85;
  int hc = hcbase + j;
  int bx = blockIdx.x;                  // 0..31: 8 y-tiles x 4 x-tiles
  int y0 = (bx >> 2) * 32;
  int x0 = (bx & 3) * 64;
  int tid = threadIdx.x;

  __shared__ u16 sT[2][36][88];   // t planes (bf16); row = gy-(y0-2); col = gx-(x0-8)
  __shared__ u16 sD[2][34][88];   // d planes (bf16); row = gy-(y0-1); col = (gx-x0)+4

  const u16* t1 = t + (size_t)(b*170 + j) * PL;
  const u16* t2 = t + (size_t)(b*170 + 85 + j) * PL;

  // ---- stage t halo (raw bf16 copy): 2 planes x 36 rows x 10 aligned chunks ----
  #pragma unroll
  for (int it = 0; it < 3; ++it) {
    int idx = tid + it*256;
    if (idx < 720) {
      int pl = idx / 360, rem = idx % 360;
      int r = rem / 10, ch = rem % 10;
      int gy = y0 + r - 2;
      int gxb = x0 - 8 + ch*8;
      ushort8 v = {0,0,0,0,0,0,0,0};
      if (gy >= 0 && gy < 256 && gxb >= 0 && gxb <= 248)
        v = *reinterpret_cast<const ushort8*>((pl ? t2 : t1) + gy*256 + gxb);
      *reinterpret_cast<ushort8*>(&sT[pl][r][ch*8]) = v;
    }
  }
  __syncthreads();

  // ---- d = conv3(t), zeroed outside image: 2 planes x 34 rows x 9 segs of 8 ----
  #pragma unroll
  for (int it = 0; it < 3; ++it) {
    int idx = tid + it*256;
    if (idx < 612) {
      int pl = idx / 306, rem = idx % 306;
      int r = rem / 9, si = rem % 9;          // d row rel y = r-1; seg cols rel x = si*8-4 ..+7
      int gy = y0 + r - 1;
      ushort8 u0 = *reinterpret_cast<const ushort8*>(&sT[pl][r  ][si*8]);
      ushort8 u0b= *reinterpret_cast<const ushort8*>(&sT[pl][r  ][si*8+8]);
      ushort8 u1 = *reinterpret_cast<const ushort8*>(&sT[pl][r+1][si*8]);
      ushort8 u1b= *reinterpret_cast<const ushort8*>(&sT[pl][r+1][si*8+8]);
      ushort8 u2 = *reinterpret_cast<const ushort8*>(&sT[pl][r+2][si*8]);
      ushort8 u2b= *reinterpret_cast<const ushort8*>(&sT[pl][r+2][si*8+8]);
      float w[3][16];
      #pragma unroll
      for (int e = 0; e < 8; ++e) {
        w[0][e] = bf2f((u16)u0[e]); w[0][8+e] = bf2f((u16)u0b[e]);
        w[1][e] = bf2f((u16)u1[e]); w[1][8+e] = bf2f((u16)u1b[e]);
        w[2][e] = bf2f((u16)u2[e]); w[2][8+e] = bf2f((u16)u2b[e]);
      }
      const float* kp = wdw + (pl ? (170+hc) : hc)*9;
      float kk[9];
      #pragma unroll
      for (int i=0;i<9;++i) kk[i] = kp[i];
      int gx0 = x0 + si*8 - 4;
      bool rowok = (gy >= 0 && gy < 256);
      ushort8 dv;
      #pragma unroll
      for (int jj = 0; jj < 8; ++jj) {
        float a = 0.f;
        #pragma unroll
        for (int i=0;i<3;++i)
          #pragma unroll
          for (int dk=0;dk<3;++dk)
            a += kk[i*3+dk] * w[i][jj+dk+3];
        int gx = gx0 + jj;
        bool ok = rowok && gx >= 0 && gx < 256;
        dv[jj] = ok ? f2bf(a) : (u16)0;
      }
      *reinterpret_cast<ushort8*>(&sD[pl][r][si*8]) = dv;
    }
  }
  __syncthreads();

  // ---- second conv + tanh gate, 8 outputs per thread ----
  int ry = tid >> 3, seg = tid & 7;     // output row ry (0..31), cols x0+seg*8..+7
  float x1[8], x2[8];
  #pragma unroll
  for (int pl = 0; pl < 2; ++pl) {
    ushort8 u0 = *reinterpret_cast<const ushort8*>(&sD[pl][ry  ][seg*8]);
    ushort8 u0b= *reinterpret_cast<const ushort8*>(&sD[pl][ry  ][seg*8+8]);
    ushort8 u1 = *reinterpret_cast<const ushort8*>(&sD[pl][ry+1][seg*8]);
    ushort8 u1b= *reinterpret_cast<const ushort8*>(&sD[pl][ry+1][seg*8+8]);
    ushort8 u2 = *reinterpret_cast<const ushort8*>(&sD[pl][ry+2][seg*8]);
    ushort8 u2b= *reinterpret_cast<const ushort8*>(&sD[pl][ry+2][seg*8+8]);
    float w[3][16];
    #pragma unroll
    for (int e = 0; e < 8; ++e) {
      w[0][e] = bf2f((u16)u0[e]); w[0][8+e] = bf2f((u16)u0b[e]);
      w[1][e] = bf2f((u16)u1[e]); w[1][8+e] = bf2f((u16)u1b[e]);
      w[2][e] = bf2f((u16)u2[e]); w[2][8+e] = bf2f((u16)u2b[e]);
    }
    const float* kp = (pl ? wdw2 : wdw1) + hc*9;
    float kk[9];
    #pragma unroll
    for (int i=0;i<9;++i) kk[i] = kp[i];
    #pragma unroll
    for (int jj = 0; jj < 8; ++jj) {
      float a = 0.f;
      #pragma unroll
      for (int i=0;i<3;++i)
        #pragma unroll
        for (int dk=0;dk<3;++dk)
          a += kk[i*3+dk] * w[i][jj+dk+3];
      float dc = w[1][jj+4];
      float g = fast_tanh(a) + dc;
      if (pl) x2[jj] = g; else x1[jj] = g;
    }
  }
  ushort8 o;
  #pragma unroll
  for (int jj = 0; jj < 8; ++jj) o[jj] = f2bf(x1[jj]*x2[jj]);
  int gy = y0 + ry;
  *reinterpret_cast<ushort8*>(
      P + ((size_t)(b*170 + hcbase + j))*PL + gy*256 + x0 + seg*8) = o;
}

// ---------- IEL out-GEMM: out[b][o][px] += Wh[o][:] . P[b][:][px], K=170 pad 192 ----------
__global__ __launch_bounds__(256) void iel_gemm(
    const u16* __restrict__ Wh, const u16* __restrict__ P,
    float* __restrict__ out) {
  int b  = blockIdx.y;
  int p0 = blockIdx.x * 256;
  int tid = threadIdx.x;
  int lane = tid & 63, wv = tid >> 6;
  int col = lane & 15, kg = lane >> 4;
  int n0 = wv * 64;
  __shared__ u16 shP[256][36];
  f32x4 acc[4][4];
  #pragma unroll
  for (int mt=0;mt<4;++mt)
    #pragma unroll
    for (int nt=0;nt<4;++nt) acc[mt][nt] = (f32x4){0.f,0.f,0.f,0.f};

  int kk = tid & 31, q = tid >> 5;
  for (int c = 0; c < 6; ++c) {
    int hcl = c*32 + kk;
    ushort8 v[4];
    if (hcl < 170) {
      const u16* src = P + (size_t)(b*170 + hcl)*PL + p0 + q*32;
      #pragma unroll
      for (int jj=0;jj<4;++jj) v[jj] = *reinterpret_cast<const ushort8*>(src + jj*8);
    } else {
      #pragma unroll
      for (int jj=0;jj<4;++jj) v[jj] = (ushort8){0,0,0,0,0,0,0,0};
    }
    __syncthreads();            // previous chunk's MFMA reads complete
    #pragma unroll
    for (int jj=0;jj<4;++jj)
      #pragma unroll
      for (int i=0;i<8;++i) shP[q*32 + jj*8 + i][kk] = v[jj][i];
    __syncthreads();
    #pragma unroll
    for (int nt = 0; nt < 4; ++nt) {
      int px = n0 + nt*16 + col;
      const bf16x4* pp = reinterpret_cast<const bf16x4*>(&shP[px][kg*8]);
      bf16x4 plo = pp[0], phi = pp[1];
      bf16x8 bfrag;
      #pragma unroll
      for (int jj=0;jj<4;++jj){ bfrag[jj]=plo[jj]; bfrag[4+jj]=phi[jj]; }
      #pragma unroll
      for (int mt = 0; mt < 4; ++mt) {
        bf16x8 a = *reinterpret_cast<const bf16x8*>(&Wh[(mt*16+col)*192 + c*32 + kg*8]);
        acc[mt][nt] = __builtin_amdgcn_mfma_f32_16x16x32_bf16(a, bfrag, acc[mt][nt], 0,0,0);
      }
    }
  }
  #pragma unroll
  for (int mt=0; mt<4; ++mt)
    #pragma unroll
    for (int nt=0; nt<4; ++nt)
      #pragma unroll
      for (int r=0; r<4; ++r){
        int o = mt*16 + kg*4 + r;
        size_t idx = ((size_t)(b*64 + o))*PL + p0 + n0 + nt*16 + col;
        out[idx] += acc[mt][nt][r];
      }
}

extern "C" void kernel_launch(void* const* d_in, const int* in_sizes, int n_in,
                              void* d_out, int out_size, void* d_ws, size_t ws_size,
                              hipStream_t stream) {
  const float* x      = (const float*)d_in[0];
  const float* y      = (const float*)d_in[1];
  const float* lnw    = (const float*)d_in[2];
  const float* lnb    = (const float*)d_in[3];
  const float* temp   = (const float*)d_in[4];
  const float* wq     = (const float*)d_in[5];
  const float* wq_dw  = (const float*)d_in[6];
  const float* wkv    = (const float*)d_in[7];
  const float* wkv_dw = (const float*)d_in[8];
  const float* wproj  = (const float*)d_in[9];
  const float* w_in   = (const float*)d_in[10];
  const float* w_dw   = (const float*)d_in[11];
  const float* w_dw1  = (const float*)d_in[12];
  const float* w_dw2  = (const float*)d_in[13];
  const float* w_out  = (const float*)d_in[14];

  // ---- arena: 128KB weight head + 178.26MB data = 178.4 MB peak (proven-safe) ----
  char* base = (char*)d_ws;
  u16* Wq_b    = (u16*)(base + 0);        //  8,192 B
  u16* Wkv_b   = (u16*)(base + 8192);     // 16,384 B
  u16* Wp0     = (u16*)(base + 24576);    // 22,528 B
  u16* Wp1     = (u16*)(base + 47104);    // 22,528 B
  u16* Wproj_b = (u16*)(base + 69632);    //  8,192 B
  u16* Wh      = (u16*)(base + 77824);    // 24,576 B (ends 102,400)
  char* A = base + 131072;                // 178,257,920 B data region

  // CAB phase
  u16*  kvpre = (u16*)A;                  // 67,108,864 B [b][128][PL]
  u16*  kvd   = (u16*)(A + 89128960);     // 67,108,864 B (ends 156,237,824)
  u16*  qpre  = (u16*)A;                  // 33,554,432 B (kvpre dead)
  u16*  qd    = (u16*)(A + 33554432);     // 33,554,432 B (ends 67,108,864)
  float* part = (float*)A;                // 655,360 B (qpre dead)
  float* red  = (float*)(A + 1048576);
  float* attnb= (float*)(A + 1572864);
  u16*  o_pm  = (u16*)(A + 4194304);      // 33,554,432 B (ends 37,748,736; qd dead)
  // IEL phase (all CAB scratch dead)
  u16*  tbuf  = (u16*)A;                  // 89,128,960 B [b][170][PL]
  u16*  Pbuf  = (u16*)(A + 89128960);     // 89,128,960 B [b][170][PL] (ends 178,257,920)
  float* xmid = (float*)d_out;

  convert_w<<<64, 256, 0, stream>>>(wq, wkv, w_in, w_out, wproj,
                                    Wq_b, Wkv_b, Wp0, Wp1, Wproj_b, Wh);

  // ---- CAB ----
  ln_gemm<<<dim3(256,4), 256, 0, stream>>>(y, lnw, lnb, Wkv_b, kvpre, 8, 128);
  dwconv3v<<<dim3(32,512), 256, 0, stream>>>(kvpre, wkv_dw, kvd, 128);
  ln_gemm<<<dim3(256,4), 256, 0, stream>>>(x, lnw, lnb, Wq_b, qpre, 4, 64);
  dwconv3v<<<dim3(32,256), 256, 0, stream>>>(qpre, wq_dw, qd, 64);
  attn_reduce1<<<dim3(64,32), 256, 0, stream>>>((const bf16*)qd, (const bf16*)kvd, part);
  attn_reduce2<<<32, 128, 0, stream>>>(part, red);
  attn_softmax<<<1, 64, 0, stream>>>(red, temp, attnb);
  attn_pv<<<1024, 256, 0, stream>>>((const bf16*)kvd, attnb, o_pm);
  gemm_proj<<<dim3(256,4), 256, 0, stream>>>(Wproj_b, o_pm, x, xmid);

  // ---- IEL: two half passes into full P, one K=192 GEMM + residual ----
  ln_gemm<<<dim3(256,4), 256, 0, stream>>>(xmid, lnw, lnb, Wp0, tbuf, 11, 170);
  iel_gate2<<<dim3(32,340), 256, 0, stream>>>(tbuf, w_dw, w_dw1, w_dw2, Pbuf, 0);
  ln_gemm<<<dim3(256,4), 256, 0, stream>>>(xmid, lnw, lnb, Wp1, tbuf, 11, 170);
  iel_gate2<<<dim3(32,340), 256, 0, stream>>>(tbuf, w_dw, w_dw1, w_dw2, Pbuf, 85);
  iel_gemm<<<dim3(256,4), 256, 0, stream>>>(Wh, Pbuf, xmid);
}